// Round 5
// baseline (2244.633 us; speedup 1.0000x reference)
//
#include <hip/hip_runtime.h>
#include <cstdint>
#include <cstddef>

// PPmodel_all_preprocess — MI355X, round 5: MFMA for the three big GEMMs.
//
// Round-4 counters: k_scatter 580us = exactly the fp32-VALU structural limit
// (219us FLOP floor / 55% issue eff / 22% occupancy). Path forward is matrix
// cores: 32x32x16 bf16 MFMA, orientation M=channels N=points, so the C/D
// layout (col=lane&31=pt, row=(reg&3)+8*(reg>>2)+4*(lane>>5)=ch) gives each
// lane 4-consecutive-channel groups -> direct u64 atomic packs / ushort4
// stores. Weights pre-transposed to bf16 FRAG-LAYOUT by k_prepw so LDS
// staging is a memcpy and all frag ds_read_b128 are lane-contiguous
// (conflict-free). B (activations) register-resident per wave; A streamed
// from LDS at 1KB/MFMA (LDS-BW-bound ~500 TF effective, ~8x the fp32 floor).
//
// Workspace layout (peak ~192.9 MiB):
//   [0, 64MB)        y3   (P x 256 bf16, RAW x2@W3 — bn3 fold applied later)
//   [64MB, 96MB)     y1   (P x 64 f32)    dead after k_lin2
//   [96MB, 160MB)    y2   (P x 128 f32)   dead after k_lin3
//   [64MB, 192MB)    pooled (S x 512 u16-encoded) — zeroed AFTER k_lin3
//   [192MB, +512KB)  counts (S u32)
//   [+512KB, +4KB)   stats (8+8 | 64+64 | 128+128 | 256+256 f32)
//   then W3F 64KB | W4F 256KB | WcF 32KB (bf16 frag-layout weights)

#define P_TOT  131072
#define HWSZ   65536
#define WGRID  256
#define S_TOT  131072
#define EPS    1e-5f
#define CNTF   131072.0f

#define OFF_Y3    0ull
#define OFF_Y1    67108864ull
#define OFF_Y2    100663296ull
#define OFF_POOL  67108864ull
#define OFF_CNT   201326592ull
#define OFF_ST    201850880ull
#define OFF_W3F   201854976ull
#define OFF_W4F   201920512ull
#define OFF_WCF   202182656ull

typedef __attribute__((ext_vector_type(8)))  short bf16x8;
typedef __attribute__((ext_vector_type(16))) float f32x16;

// ---- bf16 helpers (manual, RNE) ----
__device__ __forceinline__ unsigned f2bf(float f) {
    unsigned u = __float_as_uint(f);
    return (u + 0x7FFFu + ((u >> 16) & 1u)) >> 16;   // RNE, finite inputs
}
__device__ __forceinline__ unsigned enc16(unsigned h) {  // monotonic order encode
    return (h & 0x8000u) ? (~h & 0xFFFFu) : (h | 0x8000u);
}
__device__ __forceinline__ float bf2f(unsigned h) {
    return __uint_as_float(h << 16);
}

__device__ __forceinline__ unsigned long long pmax4(unsigned long long a,
                                                    unsigned long long b) {
    unsigned long long r = 0;
    #pragma unroll
    for (int i = 0; i < 4; ++i) {
        unsigned long long ai = (a >> (16 * i)) & 0xFFFFull;
        unsigned long long bi = (b >> (16 * i)) & 0xFFFFull;
        r |= (ai > bi ? ai : bi) << (16 * i);
    }
    return r;
}
__device__ __forceinline__ void amax4(unsigned long long* addr,
                                      unsigned long long v) {
    unsigned long long old = *addr;
    while (true) {
        unsigned long long m = pmax4(old, v);
        if (m == old) return;
        unsigned long long prev = atomicCAS(addr, old, m);
        if (prev == old) return;
        old = prev;
    }
}

// ---- zero-fill (graph-capture-safe memset replacement) ----
__global__ __launch_bounds__(256) void k_zero(uint4* __restrict__ p, int n_u4) {
    int i = blockIdx.x * blockDim.x + threadIdx.x;
    if (i < n_u4) p[i] = make_uint4(0u, 0u, 0u, 0u);
}

// ---- Prep: W3/W4/Wc -> bf16 frag-layout (A operand, M=out-ch, 32x32x16) ----
// frag f for (mt,ks): lane l holds A[m=mt*32+(l&31)][k=ks*16+(l>>5)*8+j],
// j=0..7, stored as one uint4 (8 bf16) at dst[f*64 + l].
__global__ __launch_bounds__(256) void k_prepw(
    const float* __restrict__ W3, const float* __restrict__ W4,
    const float* __restrict__ Wc, uint4* __restrict__ W3F,
    uint4* __restrict__ W4F, uint4* __restrict__ WcF)
{
    int gw = (blockIdx.x * 256 + threadIdx.x) >> 6;
    int l = threadIdx.x & 63;
    const float* W; uint4* dst; int M, mt, ks, fi;
    if (gw < 64)       { fi = gw;       W = W3; dst = W3F; M = 256; mt = fi >> 3; ks = fi & 7;  }
    else if (gw < 320) { fi = gw - 64;  W = W4; dst = W4F; M = 512; mt = fi >> 4; ks = fi & 15; }
    else               { fi = gw - 320; W = Wc; dst = WcF; M = 32;  mt = 0;      ks = fi;      }
    int m = mt * 32 + (l & 31);
    int k0 = ks * 16 + (l >> 5) * 8;
    unsigned p[4];
    #pragma unroll
    for (int jj = 0; jj < 4; ++jj) {
        unsigned lo = f2bf(W[(size_t)(k0 + 2*jj)     * M + m]);
        unsigned hi = f2bf(W[(size_t)(k0 + 2*jj + 1) * M + m]);
        p[jj] = lo | (hi << 16);
    }
    dst[(size_t)fi * 64 + l] = make_uint4(p[0], p[1], p[2], p[3]);
}

// ---- Kernel 1: bn0 raw stats (8 ch sum/sumsq) + per-voxel point counts ----
__global__ __launch_bounds__(256) void k_stats0(
    const float* __restrict__ pt, const int* __restrict__ xy,
    float* __restrict__ st0, unsigned* __restrict__ counts)
{
    int tid = blockIdx.x * blockDim.x + threadIdx.x;
    int stride = gridDim.x * blockDim.x;
    float s[8] = {0,0,0,0,0,0,0,0}, q[8] = {0,0,0,0,0,0,0,0};
    for (int p = tid; p < P_TOT; p += stride) {
        const float4* f4 = (const float4*)(pt + (size_t)p * 8);
        float4 a = f4[0], b = f4[1];
        float v[8] = {a.x,a.y,a.z,a.w,b.x,b.y,b.z,b.w};
        #pragma unroll
        for (int k = 0; k < 8; ++k) { s[k] += v[k]; q[k] += v[k]*v[k]; }
        int key = (p >> 16) * HWSZ + xy[2*p] * WGRID + xy[2*p + 1];
        atomicAdd(&counts[key], 1u);
    }
    #pragma unroll
    for (int k = 0; k < 8; ++k) {
        #pragma unroll
        for (int off = 32; off > 0; off >>= 1) {
            s[k] += __shfl_down(s[k], off);
            q[k] += __shfl_down(q[k], off);
        }
    }
    if ((threadIdx.x & 63) == 0) {
        #pragma unroll
        for (int k = 0; k < 8; ++k) {
            atomicAdd(&st0[k], s[k]);
            atomicAdd(&st0[8 + k], q[k]);
        }
    }
}

// ---- Kernel 2: x0 = bn0(feats); y1 = x0 @ W1 [P,64]; bn1 stats ----
__global__ __launch_bounds__(256) void k_lin1(
    const float* __restrict__ pt, const float* __restrict__ g0,
    const float* __restrict__ b0, const float* __restrict__ W1,
    const float* __restrict__ st0, float* __restrict__ y1,
    float* __restrict__ st1)
{
    __shared__ float x0s[64 * 8];
    __shared__ float w1s[8 * 64];
    __shared__ float sc0s[8], sh0s[8];
    __shared__ float red[256];
    const int tid = threadIdx.x;
    const int pbase = blockIdx.x * 64;

    if (tid < 8) {
        float mu = st0[tid] * (1.0f / CNTF);
        float var = st0[8 + tid] * (1.0f / CNTF) - mu * mu;
        float rs = rsqrtf(var + EPS);
        sc0s[tid] = rs * g0[tid];
        sh0s[tid] = b0[tid] - mu * rs * g0[tid];
    }
    __syncthreads();
    if (tid < 128) {
        ((float4*)w1s)[tid] = ((const float4*)W1)[tid];
        float4 f = ((const float4*)(pt + (size_t)pbase * 8))[tid];
        int c = (tid & 1) * 4;
        f.x = fmaf(f.x, sc0s[c + 0], sh0s[c + 0]);
        f.y = fmaf(f.y, sc0s[c + 1], sh0s[c + 1]);
        f.z = fmaf(f.z, sc0s[c + 2], sh0s[c + 2]);
        f.w = fmaf(f.w, sc0s[c + 3], sh0s[c + 3]);
        ((float4*)x0s)[tid] = f;
    }
    __syncthreads();
    const int c = tid & 63;
    const int psub = tid >> 6;
    float ssum = 0.f, ssq = 0.f;
    #pragma unroll
    for (int i = 0; i < 16; ++i) {
        int pl = psub * 16 + i;
        float acc = 0.f;
        #pragma unroll
        for (int k = 0; k < 8; ++k)
            acc = fmaf(x0s[pl * 8 + k], w1s[k * 64 + c], acc);
        y1[(size_t)(pbase + pl) * 64 + c] = acc;
        ssum += acc; ssq += acc * acc;
    }
    red[tid] = ssum; __syncthreads();
    if (tid < 64) atomicAdd(&st1[c], red[c] + red[c+64] + red[c+128] + red[c+192]);
    __syncthreads();
    red[tid] = ssq; __syncthreads();
    if (tid < 64) atomicAdd(&st1[64 + c], red[c] + red[c+64] + red[c+128] + red[c+192]);
}

// ---- Kernel 3: x1 = relu(bn1(y1)); y2 = x1 @ W2 [P,128]; bn2 stats ----
__global__ __launch_bounds__(256) void k_lin2(
    const float* __restrict__ y1, const float* __restrict__ g1,
    const float* __restrict__ b1, const float* __restrict__ W2,
    const float* __restrict__ st1, float* __restrict__ y2,
    float* __restrict__ st2)
{
    __shared__ float w2s[64 * 128];   // 32 KB
    __shared__ float x1s[16 * 64];    // 4 KB
    __shared__ float sc1s[64], sh1s[64];
    __shared__ float red[256];
    const int tid = threadIdx.x;
    const int pbase = blockIdx.x * 16;

    if (tid < 64) {
        float mu = st1[tid] * (1.0f / CNTF);
        float var = st1[64 + tid] * (1.0f / CNTF) - mu * mu;
        float rs = rsqrtf(var + EPS);
        sc1s[tid] = rs * g1[tid];
        sh1s[tid] = b1[tid] - mu * rs * g1[tid];
    }
    #pragma unroll
    for (int r = 0; r < 8; ++r)
        ((float4*)w2s)[r * 256 + tid] = ((const float4*)W2)[r * 256 + tid];
    __syncthreads();
    {
        float4 v = ((const float4*)(y1 + (size_t)pbase * 64))[tid];
        int c = (tid & 15) * 4;
        v.x = fmaxf(fmaf(v.x, sc1s[c+0], sh1s[c+0]), 0.f);
        v.y = fmaxf(fmaf(v.y, sc1s[c+1], sh1s[c+1]), 0.f);
        v.z = fmaxf(fmaf(v.z, sc1s[c+2], sh1s[c+2]), 0.f);
        v.w = fmaxf(fmaf(v.w, sc1s[c+3], sh1s[c+3]), 0.f);
        ((float4*)x1s)[tid] = v;
    }
    __syncthreads();
    const int c = tid & 127;
    const int psub = tid >> 7;
    float acc[8] = {0,0,0,0,0,0,0,0};
    #pragma unroll 4
    for (int k = 0; k < 64; k += 4) {
        float w0 = w2s[(k+0)*128 + c];
        float w1_ = w2s[(k+1)*128 + c];
        float w2_ = w2s[(k+2)*128 + c];
        float w3_ = w2s[(k+3)*128 + c];
        #pragma unroll
        for (int j = 0; j < 8; ++j) {
            const float4 xv = *(const float4*)&x1s[(psub*8 + j)*64 + k];
            acc[j] = fmaf(xv.x, w0, acc[j]);
            acc[j] = fmaf(xv.y, w1_, acc[j]);
            acc[j] = fmaf(xv.z, w2_, acc[j]);
            acc[j] = fmaf(xv.w, w3_, acc[j]);
        }
    }
    float ssum = 0.f, ssq = 0.f;
    #pragma unroll
    for (int j = 0; j < 8; ++j) {
        float vo = acc[j];
        y2[(size_t)(pbase + psub*8 + j) * 128 + c] = vo;
        ssum += vo; ssq += vo * vo;
    }
    red[tid] = ssum; __syncthreads();
    if (tid < 128) atomicAdd(&st2[tid], red[tid] + red[tid + 128]);
    __syncthreads();
    red[tid] = ssq; __syncthreads();
    if (tid < 128) atomicAdd(&st2[128 + tid], red[tid] + red[tid + 128]);
}

// ---- Kernel 4 (MFMA): y3 = bf16(relu(bn2(y2)) @ W3) [P,256]; bn3 stats ----
// Block: 32 pts, 4 waves x 2 M-tiles (256 ch). K=128 -> 8 K-steps, B resident.
__global__ __launch_bounds__(256, 4) void k_lin3(
    const float* __restrict__ y2, const float* __restrict__ g2,
    const float* __restrict__ b2, const uint4* __restrict__ W3F,
    const float* __restrict__ st2, unsigned short* __restrict__ y3,
    float* __restrict__ st3)
{
    __shared__ float sc2s[128], sh2s[128];
    __shared__ uint4 w3s[2048];        // 32 KB: 32 frags [mt(8)][ksl(4)]
    const int tid = threadIdx.x, l = tid & 63, w = tid >> 6;
    const int pbase = blockIdx.x * 32;

    if (tid < 128) {
        float g = g2[tid];
        float mu = st2[tid] * (1.0f / CNTF);
        float var = st2[128 + tid] * (1.0f / CNTF) - mu * mu;
        float rs = rsqrtf(var + EPS);
        sc2s[tid] = rs * g;
        sh2s[tid] = b2[tid] - mu * rs * g;
    }
    __syncthreads();

    const int n = l & 31, q = l >> 5;
    bf16x8 Bf[8];
    const float* yrow = y2 + (size_t)(pbase + n) * 128 + q * 8;
    #pragma unroll
    for (int ks = 0; ks < 8; ++ks) {
        float4 v0 = *(const float4*)(yrow + ks * 16);
        float4 v1 = *(const float4*)(yrow + ks * 16 + 4);
        int k0 = ks * 16 + q * 8;
        float e[8] = {v0.x,v0.y,v0.z,v0.w,v1.x,v1.y,v1.z,v1.w};
        union { bf16x8 v; unsigned u[4]; } cv;
        #pragma unroll
        for (int jj = 0; jj < 4; ++jj) {
            float a0 = fmaxf(fmaf(e[2*jj],   sc2s[k0+2*jj],   sh2s[k0+2*jj]),   0.f);
            float a1 = fmaxf(fmaf(e[2*jj+1], sc2s[k0+2*jj+1], sh2s[k0+2*jj+1]), 0.f);
            cv.u[jj] = f2bf(a0) | (f2bf(a1) << 16);
        }
        Bf[ks] = cv.v;
    }
    f32x16 acc[2];
    #pragma unroll
    for (int i = 0; i < 2; ++i)
        #pragma unroll
        for (int r = 0; r < 16; ++r) acc[i][r] = 0.f;

    for (int kc = 0; kc < 2; ++kc) {
        __syncthreads();
        #pragma unroll
        for (int r = 0; r < 8; ++r) {
            int idx = r * 256 + tid;
            int fic = idx >> 6, li = idx & 63;
            int mt = fic >> 2, ksl = fic & 3;
            w3s[idx] = W3F[(size_t)(mt * 8 + kc * 4 + ksl) * 64 + li];
        }
        __syncthreads();
        #pragma unroll
        for (int ksl = 0; ksl < 4; ++ksl) {
            #pragma unroll
            for (int i = 0; i < 2; ++i) {
                union { uint4 u; bf16x8 v; } av;
                av.u = w3s[((w * 2 + i) * 4 + ksl) * 64 + l];
                acc[i] = __builtin_amdgcn_mfma_f32_32x32x16_bf16(
                    av.v, Bf[kc * 4 + ksl], acc[i], 0, 0, 0);
            }
        }
    }
    // epilogue: y3 store (raw, no fold) + bn3 raw stats
    #pragma unroll
    for (int i = 0; i < 2; ++i) {
        int mtb = (w * 2 + i) * 32;
        #pragma unroll
        for (int g = 0; g < 4; ++g) {
            int ch0 = mtb + 8 * g + 4 * q;
            ushort4 pk;
            pk.x = (unsigned short)f2bf(acc[i][4*g+0]);
            pk.y = (unsigned short)f2bf(acc[i][4*g+1]);
            pk.z = (unsigned short)f2bf(acc[i][4*g+2]);
            pk.w = (unsigned short)f2bf(acc[i][4*g+3]);
            *(ushort4*)(y3 + (size_t)(pbase + n) * 256 + ch0) = pk;
        }
    }
    #pragma unroll
    for (int i = 0; i < 2; ++i) {
        int mtb = (w * 2 + i) * 32;
        #pragma unroll
        for (int r = 0; r < 16; ++r) {
            float s = acc[i][r], sq = s * s;
            #pragma unroll
            for (int off = 16; off > 0; off >>= 1) {
                s  += __shfl_xor(s, off);
                sq += __shfl_xor(sq, off);
            }
            if ((l & 31) == 0) {
                int ch = mtb + (r & 3) + 8 * (r >> 2) + 4 * q;
                atomicAdd(&st3[ch], s);
                atomicAdd(&st3[256 + ch], sq);
            }
        }
    }
}

// ---- Kernel 5 (MFMA): x4 = relu(bn3(y3)) @ W4; packed-u64 scatter max ----
// Block: 32 pts, 4 waves x 4 M-tiles (512 ch). K=256 -> 16 K-steps, B resident.
__global__ __launch_bounds__(256, 2) void k_scatter(
    const unsigned short* __restrict__ y3, const float* __restrict__ g3,
    const float* __restrict__ b3, const uint4* __restrict__ W4F,
    const float* __restrict__ st3, const int* __restrict__ xy,
    unsigned long long* __restrict__ pool64)
{
    __shared__ float sc3s[256], sh3s[256];
    __shared__ uint4 w4s[2048];        // 32 KB: 32 frags [mt(16)][ksl(2)]
    const int tid = threadIdx.x, l = tid & 63, w = tid >> 6;
    const int pbase = blockIdx.x * 32;

    {
        float g = g3[tid];
        float mu = st3[tid] * (1.0f / CNTF);
        float var = st3[256 + tid] * (1.0f / CNTF) - mu * mu;
        float rs = rsqrtf(var + EPS);
        sc3s[tid] = rs * g;
        sh3s[tid] = b3[tid] - mu * rs * g;
    }
    __syncthreads();

    const int n = l & 31, q = l >> 5;
    const int p = pbase + n;
    bf16x8 Bf[16];
    const unsigned short* yrow = y3 + (size_t)p * 256 + q * 8;
    #pragma unroll
    for (int ks = 0; ks < 16; ++ks) {
        uint4 e = *(const uint4*)(yrow + ks * 16);
        int k0 = ks * 16 + q * 8;
        unsigned eu[4] = {e.x, e.y, e.z, e.w};
        union { bf16x8 v; unsigned u[4]; } cv;
        #pragma unroll
        for (int jj = 0; jj < 4; ++jj) {
            float a0 = fmaxf(fmaf(bf2f(eu[jj] & 0xFFFFu), sc3s[k0+2*jj],   sh3s[k0+2*jj]),   0.f);
            float a1 = fmaxf(fmaf(bf2f(eu[jj] >> 16),     sc3s[k0+2*jj+1], sh3s[k0+2*jj+1]), 0.f);
            cv.u[jj] = f2bf(a0) | (f2bf(a1) << 16);
        }
        Bf[ks] = cv.v;
    }
    f32x16 acc[4];
    #pragma unroll
    for (int i = 0; i < 4; ++i)
        #pragma unroll
        for (int r = 0; r < 16; ++r) acc[i][r] = 0.f;

    for (int kc = 0; kc < 8; ++kc) {
        __syncthreads();
        #pragma unroll
        for (int r = 0; r < 8; ++r) {
            int idx = r * 256 + tid;
            int fic = idx >> 6, li = idx & 63;
            int mt = fic >> 1, ksl = fic & 1;
            w4s[idx] = W4F[(size_t)(mt * 16 + kc * 2 + ksl) * 64 + li];
        }
        __syncthreads();
        #pragma unroll
        for (int ksl = 0; ksl < 2; ++ksl) {
            #pragma unroll
            for (int i = 0; i < 4; ++i) {
                union { uint4 u; bf16x8 v; } av;
                av.u = w4s[((w * 4 + i) * 2 + ksl) * 64 + l];
                acc[i] = __builtin_amdgcn_mfma_f32_32x32x16_bf16(
                    av.v, Bf[kc * 2 + ksl], acc[i], 0, 0, 0);
            }
        }
    }
    // epilogue: u64 packed atomic max, 4 consecutive chs per reg-quad
    int key = (p >> 16) * HWSZ + xy[2*p] * WGRID + xy[2*p + 1];
    unsigned long long* kp = pool64 + (size_t)key * 128;
    #pragma unroll
    for (int i = 0; i < 4; ++i) {
        int mtb = (w * 4 + i) * 32;
        #pragma unroll
        for (int g = 0; g < 4; ++g) {
            int ch0 = mtb + 8 * g + 4 * q;
            unsigned long long v =
                  (unsigned long long)enc16(f2bf(acc[i][4*g+0]))
                | ((unsigned long long)enc16(f2bf(acc[i][4*g+1])) << 16)
                | ((unsigned long long)enc16(f2bf(acc[i][4*g+2])) << 32)
                | ((unsigned long long)enc16(f2bf(acc[i][4*g+3])) << 48);
            amax4(kp + (ch0 >> 2), v);
        }
    }
}

// ---- Kernel 6 (MFMA): comp = relu(pooled @ Wc); transpose to [B,CMP,H,W] ----
// Block: 128 voxels (4 waves x 32), 1 M-tile (32 ch), K=512 -> 32 K-steps.
__global__ __launch_bounds__(256, 4) void k_out(
    const unsigned short* __restrict__ pooled, const unsigned* __restrict__ counts,
    const uint4* __restrict__ WcF, float* __restrict__ out)
{
    __shared__ uint4 wcs[2048];        // 32 KB: full WcF (32 frags)
    const int tid = threadIdx.x, l = tid & 63, w = tid >> 6;
    const int sbase = blockIdx.x * 128;
    #pragma unroll
    for (int r = 0; r < 8; ++r) {
        int idx = r * 256 + tid;
        wcs[idx] = WcF[idx];
    }
    __syncthreads();
    const int n = l & 31, q = l >> 5;
    const int s = sbase + w * 32 + n;
    const unsigned short* prow = pooled + (size_t)s * 512 + q * 8;
    f32x16 acc;
    #pragma unroll
    for (int r = 0; r < 16; ++r) acc[r] = 0.f;

    for (int ks = 0; ks < 32; ++ks) {
        uint4 e = *(const uint4*)(prow + ks * 16);
        unsigned eu[4] = {e.x, e.y, e.z, e.w};
        union { bf16x8 v; unsigned u[4]; } bv;
        #pragma unroll
        for (int jj = 0; jj < 4; ++jj) {
            unsigned e0 = eu[jj] & 0xFFFFu, e1 = eu[jj] >> 16;
            unsigned h0 = (e0 & 0x8000u) ? (e0 & 0x7FFFu) : (~e0 & 0xFFFFu);
            unsigned h1 = (e1 & 0x8000u) ? (e1 & 0x7FFFu) : (~e1 & 0xFFFFu);
            bv.u[jj] = h0 | (h1 << 16);
        }
        union { uint4 u; bf16x8 v; } av;
        av.u = wcs[ks * 64 + l];
        acc = __builtin_amdgcn_mfma_f32_32x32x16_bf16(av.v, bv.v, acc, 0, 0, 0);
    }
    const bool occ = counts[s] > 0;
    const int b = s >> 16, hw = s & 65535;
    #pragma unroll
    for (int r = 0; r < 16; ++r) {
        int ch = (r & 3) + 8 * (r >> 2) + 4 * q;
        float x = occ ? fmaxf(acc[r], 0.f) : 0.f;
        out[(size_t)b * (32 * HWSZ) + (size_t)ch * HWSZ + hw] = x;
    }
}

extern "C" void kernel_launch(void* const* d_in, const int* in_sizes, int n_in,
                              void* d_out, int out_size, void* d_ws, size_t ws_size,
                              hipStream_t stream) {
    const float* pt = (const float*)d_in[0];
    const float* g0 = (const float*)d_in[1];
    const float* b0 = (const float*)d_in[2];
    const float* W1 = (const float*)d_in[3];
    const float* g1 = (const float*)d_in[4];
    const float* b1 = (const float*)d_in[5];
    const float* W2 = (const float*)d_in[6];
    const float* g2 = (const float*)d_in[7];
    const float* b2 = (const float*)d_in[8];
    const float* W3 = (const float*)d_in[9];
    const float* g3 = (const float*)d_in[10];
    const float* b3 = (const float*)d_in[11];
    const float* W4 = (const float*)d_in[12];
    const float* Wc = (const float*)d_in[13];
    const int*   xy = (const int*)d_in[14];
    float* out = (float*)d_out;

    char* ws = (char*)d_ws;
    unsigned short*     y3     = (unsigned short*)(ws + OFF_Y3);
    float*              y1     = (float*)(ws + OFF_Y1);
    float*              y2     = (float*)(ws + OFF_Y2);
    unsigned long long* pool64 = (unsigned long long*)(ws + OFF_POOL);
    unsigned short*     pool16 = (unsigned short*)(ws + OFF_POOL);
    unsigned*           counts = (unsigned*)(ws + OFF_CNT);
    float*              st     = (float*)(ws + OFF_ST);
    uint4* W3F = (uint4*)(ws + OFF_W3F);
    uint4* W4F = (uint4*)(ws + OFF_W4F);
    uint4* WcF = (uint4*)(ws + OFF_WCF);
    float* st0 = st;         // 8 + 8
    float* st1 = st + 16;    // 64 + 64
    float* st2 = st + 144;   // 128 + 128
    float* st3 = st + 400;   // 256 + 256

    // zero counts + stats: 524288 + 4096 B = 33024 uint4
    k_zero<<<129, 256, 0, stream>>>((uint4*)(ws + OFF_CNT), 33024);
    // weights -> bf16 frag layout (352 frags = 352 waves = 88 blocks)
    k_prepw<<<88, 256, 0, stream>>>(W3, W4, Wc, W3F, W4F, WcF);

    k_stats0<<<512, 256, 0, stream>>>(pt, xy, st0, counts);
    k_lin1<<<P_TOT / 64, 256, 0, stream>>>(pt, g0, b0, W1, st0, y1, st1);
    k_lin2<<<P_TOT / 16, 256, 0, stream>>>(y1, g1, b1, W2, st1, y2, st2);
    k_lin3<<<P_TOT / 32, 256, 0, stream>>>(y2, g2, b2, W3F, st2, y3, st3);
    // y1/y2 dead -> zero pooled (0 == encoded -inf): 128 MiB = 8388608 uint4
    k_zero<<<32768, 256, 0, stream>>>((uint4*)(ws + OFF_POOL), 8388608);
    k_scatter<<<P_TOT / 32, 256, 0, stream>>>(y3, g3, b3, W4F, st3, xy, pool64);
    k_out<<<S_TOT / 128, 256, 0, stream>>>(pool16, counts, WcF, out);
}

// Round 6
// 1339.897 us; speedup vs baseline: 1.6752x; 1.6752x over previous
//
#include <hip/hip_runtime.h>
#include <cstdint>
#include <cstddef>

// PPmodel_all_preprocess — MI355X, round 6: MFMA without spills.
//
// Round-5 failure: __launch_bounds__(256,4) forced <=128 unified regs ->
// compiler spilled the register-resident B fragments (VGPR_Count 52,
// WRITE_SIZE +32MB = 32B/thread scratch) -> every MFMA waited on scratch:
// MfmaUtil 0.4%, VALUBusy 2.8%, 828us. Fix: (256,2) everywhere heavy, and
// restructure so each block stages its weight fragments ONCE (full set in
// exactly-64KB LDS) amortized over 8-16 point tiles. bn folds are applied
// by tiny in-place k_fold passes so GEMM kernels carry no scale arrays.
//
// Workspace layout (peak ~193 MiB):
//   [0, 64MB)        y3   (P x 256 bf16; raw then folded in place)
//   [64MB, 96MB)     y1   (P x 64 f32)     dead after k_lin2
//   [96MB, 128MB)    y2   (P x 128 bf16; raw then folded in place)
//   [64MB, 192MB)    pooled (S x 512 u16-encoded) — zeroed AFTER k_lin3
//   [192MB,+512KB)   counts (S u32)
//   [+512KB,+4KB)    stats (8+8 | 64+64 | 128+128 | 256+256 f32)
//   then W3F 64KB | W4F 256KB | WcF 32KB | W2F 16KB (bf16 frag layout)

#define P_TOT  131072
#define HWSZ   65536
#define WGRID  256
#define S_TOT  131072
#define EPS    1e-5f
#define CNTF   131072.0f

#define OFF_Y3    0ull
#define OFF_Y1    67108864ull
#define OFF_Y2    100663296ull
#define OFF_POOL  67108864ull
#define OFF_CNT   201326592ull
#define OFF_ST    201850880ull
#define OFF_W3F   201854976ull
#define OFF_W4F   201920512ull
#define OFF_WCF   202182656ull
#define OFF_W2F   202215424ull

typedef __attribute__((ext_vector_type(8)))  short bf16x8;
typedef __attribute__((ext_vector_type(16))) float f32x16;

// ---- bf16 helpers (manual, RNE) ----
__device__ __forceinline__ unsigned f2bf(float f) {
    unsigned u = __float_as_uint(f);
    return (u + 0x7FFFu + ((u >> 16) & 1u)) >> 16;   // RNE, finite inputs
}
__device__ __forceinline__ unsigned enc16(unsigned h) {  // monotonic order encode
    return (h & 0x8000u) ? (~h & 0xFFFFu) : (h | 0x8000u);
}
__device__ __forceinline__ float bf2f(unsigned h) {
    return __uint_as_float(h << 16);
}

__device__ __forceinline__ unsigned long long pmax4(unsigned long long a,
                                                    unsigned long long b) {
    unsigned long long r = 0;
    #pragma unroll
    for (int i = 0; i < 4; ++i) {
        unsigned long long ai = (a >> (16 * i)) & 0xFFFFull;
        unsigned long long bi = (b >> (16 * i)) & 0xFFFFull;
        r |= (ai > bi ? ai : bi) << (16 * i);
    }
    return r;
}
__device__ __forceinline__ void amax4(unsigned long long* addr,
                                      unsigned long long v) {
    unsigned long long old = *addr;
    while (true) {
        unsigned long long m = pmax4(old, v);
        if (m == old) return;
        unsigned long long prev = atomicCAS(addr, old, m);
        if (prev == old) return;
        old = prev;
    }
}

// ---- zero-fill (graph-capture-safe memset replacement) ----
__global__ __launch_bounds__(256) void k_zero(uint4* __restrict__ p, int n_u4) {
    int i = blockIdx.x * blockDim.x + threadIdx.x;
    if (i < n_u4) p[i] = make_uint4(0u, 0u, 0u, 0u);
}

// ---- Prep: W2/W3/W4/Wc -> bf16 frag layout (A operand, 32x32x16) ----
// frag fi=(mt,ks): lane l holds A[m=mt*32+(l&31)][k=ks*16+(l>>5)*8+j], j=0..7,
// one uint4 at dst[fi*64 + l].
__global__ __launch_bounds__(256) void k_prepw(
    const float* __restrict__ W2, const float* __restrict__ W3,
    const float* __restrict__ W4, const float* __restrict__ Wc,
    uint4* __restrict__ W2F, uint4* __restrict__ W3F,
    uint4* __restrict__ W4F, uint4* __restrict__ WcF)
{
    int gw = (blockIdx.x * 256 + threadIdx.x) >> 6;
    int l = threadIdx.x & 63;
    const float* W; uint4* dst; int M, mt, ks, fi;
    if (gw < 64)       { fi = gw;       W = W3; dst = W3F; M = 256; mt = fi >> 3; ks = fi & 7;  }
    else if (gw < 320) { fi = gw - 64;  W = W4; dst = W4F; M = 512; mt = fi >> 4; ks = fi & 15; }
    else if (gw < 352) { fi = gw - 320; W = Wc; dst = WcF; M = 32;  mt = 0;      ks = fi;      }
    else               { fi = gw - 352; W = W2; dst = W2F; M = 128; mt = fi >> 2; ks = fi & 3;  }
    int m = mt * 32 + (l & 31);
    int k0 = ks * 16 + (l >> 5) * 8;
    unsigned p[4];
    #pragma unroll
    for (int jj = 0; jj < 4; ++jj) {
        unsigned lo = f2bf(W[(size_t)(k0 + 2*jj)     * M + m]);
        unsigned hi = f2bf(W[(size_t)(k0 + 2*jj + 1) * M + m]);
        p[jj] = lo | (hi << 16);
    }
    dst[(size_t)fi * 64 + l] = make_uint4(p[0], p[1], p[2], p[3]);
}

// ---- In-place fold: y = bf16(relu(bn(y))) for bf16 buffer, nch pow2 ----
__global__ __launch_bounds__(256) void k_fold(
    unsigned short* __restrict__ y, const float* __restrict__ g,
    const float* __restrict__ b, const float* __restrict__ st,
    int nch, int n_u4)
{
    int i = blockIdx.x * 256 + threadIdx.x;
    if (i >= n_u4) return;
    int ch0 = (i * 8) & (nch - 1);
    uint4 e = ((const uint4*)y)[i];
    unsigned eu[4] = {e.x, e.y, e.z, e.w};
    unsigned ou[4];
    #pragma unroll
    for (int jj = 0; jj < 4; ++jj) {
        unsigned r01 = 0;
        #pragma unroll
        for (int hh = 0; hh < 2; ++hh) {
            int c = ch0 + 2*jj + hh;
            float mu = st[c] * (1.0f / CNTF);
            float var = st[nch + c] * (1.0f / CNTF) - mu * mu;
            float rs = rsqrtf(var + EPS);
            float sc = rs * g[c];
            float sh = b[c] - mu * sc;
            unsigned hb = (eu[jj] >> (16 * hh)) & 0xFFFFu;
            float x = fmaxf(fmaf(bf2f(hb), sc, sh), 0.f);
            r01 |= f2bf(x) << (16 * hh);
        }
        ou[jj] = r01;
    }
    ((uint4*)y)[i] = make_uint4(ou[0], ou[1], ou[2], ou[3]);
}

// ---- Kernel 1: bn0 raw stats (8 ch sum/sumsq) + per-voxel point counts ----
__global__ __launch_bounds__(256) void k_stats0(
    const float* __restrict__ pt, const int* __restrict__ xy,
    float* __restrict__ st0, unsigned* __restrict__ counts)
{
    int tid = blockIdx.x * blockDim.x + threadIdx.x;
    int stride = gridDim.x * blockDim.x;
    float s[8] = {0,0,0,0,0,0,0,0}, q[8] = {0,0,0,0,0,0,0,0};
    for (int p = tid; p < P_TOT; p += stride) {
        const float4* f4 = (const float4*)(pt + (size_t)p * 8);
        float4 a = f4[0], b = f4[1];
        float v[8] = {a.x,a.y,a.z,a.w,b.x,b.y,b.z,b.w};
        #pragma unroll
        for (int k = 0; k < 8; ++k) { s[k] += v[k]; q[k] += v[k]*v[k]; }
        int key = (p >> 16) * HWSZ + xy[2*p] * WGRID + xy[2*p + 1];
        atomicAdd(&counts[key], 1u);
    }
    #pragma unroll
    for (int k = 0; k < 8; ++k) {
        #pragma unroll
        for (int off = 32; off > 0; off >>= 1) {
            s[k] += __shfl_down(s[k], off);
            q[k] += __shfl_down(q[k], off);
        }
    }
    if ((threadIdx.x & 63) == 0) {
        #pragma unroll
        for (int k = 0; k < 8; ++k) {
            atomicAdd(&st0[k], s[k]);
            atomicAdd(&st0[8 + k], q[k]);
        }
    }
}

// ---- Kernel 2: x0 = bn0(feats); y1 = x0 @ W1 [P,64] f32; bn1 stats ----
__global__ __launch_bounds__(256) void k_lin1(
    const float* __restrict__ pt, const float* __restrict__ g0,
    const float* __restrict__ b0, const float* __restrict__ W1,
    const float* __restrict__ st0, float* __restrict__ y1,
    float* __restrict__ st1)
{
    __shared__ float x0s[64 * 8];
    __shared__ float w1s[8 * 64];
    __shared__ float sc0s[8], sh0s[8];
    __shared__ float red[256];
    const int tid = threadIdx.x;
    const int pbase = blockIdx.x * 64;

    if (tid < 8) {
        float mu = st0[tid] * (1.0f / CNTF);
        float var = st0[8 + tid] * (1.0f / CNTF) - mu * mu;
        float rs = rsqrtf(var + EPS);
        sc0s[tid] = rs * g0[tid];
        sh0s[tid] = b0[tid] - mu * rs * g0[tid];
    }
    __syncthreads();
    if (tid < 128) {
        ((float4*)w1s)[tid] = ((const float4*)W1)[tid];
        float4 f = ((const float4*)(pt + (size_t)pbase * 8))[tid];
        int c = (tid & 1) * 4;
        f.x = fmaf(f.x, sc0s[c + 0], sh0s[c + 0]);
        f.y = fmaf(f.y, sc0s[c + 1], sh0s[c + 1]);
        f.z = fmaf(f.z, sc0s[c + 2], sh0s[c + 2]);
        f.w = fmaf(f.w, sc0s[c + 3], sh0s[c + 3]);
        ((float4*)x0s)[tid] = f;
    }
    __syncthreads();
    const int c = tid & 63;
    const int psub = tid >> 6;
    float ssum = 0.f, ssq = 0.f;
    #pragma unroll
    for (int i = 0; i < 16; ++i) {
        int pl = psub * 16 + i;
        float acc = 0.f;
        #pragma unroll
        for (int k = 0; k < 8; ++k)
            acc = fmaf(x0s[pl * 8 + k], w1s[k * 64 + c], acc);
        y1[(size_t)(pbase + pl) * 64 + c] = acc;
        ssum += acc; ssq += acc * acc;
    }
    red[tid] = ssum; __syncthreads();
    if (tid < 64) atomicAdd(&st1[c], red[c] + red[c+64] + red[c+128] + red[c+192]);
    __syncthreads();
    red[tid] = ssq; __syncthreads();
    if (tid < 64) atomicAdd(&st1[64 + c], red[c] + red[c+64] + red[c+128] + red[c+192]);
}

// ---- Kernel 3 (MFMA): y2 = bf16(relu(bn1(y1)) @ W2) [P,128]; bn2 stats ----
// 512 blocks x 8 tiles of 32 pts. Full W2F (16KB) in LDS. Wave w -> M-tile w.
__global__ __launch_bounds__(256, 2) void k_lin2(
    const float* __restrict__ y1, const float* __restrict__ g1,
    const float* __restrict__ b1, const uint4* __restrict__ W2F,
    const float* __restrict__ st1, unsigned short* __restrict__ y2,
    float* __restrict__ st2)
{
    __shared__ uint4 w2s[1024];        // 16 KB, frag fi=(mt*4+ks)
    __shared__ float sc1s[64], sh1s[64];
    const int tid = threadIdx.x, l = tid & 63, w = tid >> 6;
    if (tid < 64) {
        float mu = st1[tid] * (1.0f / CNTF);
        float var = st1[64 + tid] * (1.0f / CNTF) - mu * mu;
        float rs = rsqrtf(var + EPS);
        sc1s[tid] = rs * g1[tid];
        sh1s[tid] = b1[tid] - mu * rs * g1[tid];
    }
    #pragma unroll
    for (int r = 0; r < 4; ++r) w2s[r * 256 + tid] = W2F[r * 256 + tid];
    __syncthreads();
    const int n = l & 31, q = l >> 5;
    float s_acc[16], q_acc[16];
    #pragma unroll
    for (int r = 0; r < 16; ++r) { s_acc[r] = 0.f; q_acc[r] = 0.f; }

    for (int t = 0; t < 8; ++t) {
        const int p = (blockIdx.x * 8 + t) * 32 + n;
        const float* yrow = y1 + (size_t)p * 64 + q * 8;
        bf16x8 Bf[4];
        #pragma unroll
        for (int ks = 0; ks < 4; ++ks) {
            float4 v0 = *(const float4*)(yrow + ks * 16);
            float4 v1 = *(const float4*)(yrow + ks * 16 + 4);
            int k0 = ks * 16 + q * 8;
            float e[8] = {v0.x,v0.y,v0.z,v0.w,v1.x,v1.y,v1.z,v1.w};
            union { bf16x8 v; unsigned u[4]; } cv;
            #pragma unroll
            for (int jj = 0; jj < 4; ++jj) {
                float a0 = fmaxf(fmaf(e[2*jj],   sc1s[k0+2*jj],   sh1s[k0+2*jj]),   0.f);
                float a1 = fmaxf(fmaf(e[2*jj+1], sc1s[k0+2*jj+1], sh1s[k0+2*jj+1]), 0.f);
                cv.u[jj] = f2bf(a0) | (f2bf(a1) << 16);
            }
            Bf[ks] = cv.v;
        }
        f32x16 acc;
        #pragma unroll
        for (int r = 0; r < 16; ++r) acc[r] = 0.f;
        #pragma unroll
        for (int ks = 0; ks < 4; ++ks) {
            union { uint4 u; bf16x8 v; } av;
            av.u = w2s[(w * 4 + ks) * 64 + l];
            acc = __builtin_amdgcn_mfma_f32_32x32x16_bf16(av.v, Bf[ks], acc, 0, 0, 0);
        }
        #pragma unroll
        for (int g = 0; g < 4; ++g) {
            int ch0 = w * 32 + 8 * g + 4 * q;
            ushort4 pk;
            pk.x = (unsigned short)f2bf(acc[4*g+0]);
            pk.y = (unsigned short)f2bf(acc[4*g+1]);
            pk.z = (unsigned short)f2bf(acc[4*g+2]);
            pk.w = (unsigned short)f2bf(acc[4*g+3]);
            *(ushort4*)(y2 + (size_t)p * 128 + ch0) = pk;
        }
        #pragma unroll
        for (int r = 0; r < 16; ++r) { s_acc[r] += acc[r]; q_acc[r] += acc[r]*acc[r]; }
    }
    #pragma unroll
    for (int r = 0; r < 16; ++r) {
        float s = s_acc[r], sq = q_acc[r];
        #pragma unroll
        for (int off = 16; off > 0; off >>= 1) {
            s  += __shfl_xor(s, off);
            sq += __shfl_xor(sq, off);
        }
        if ((l & 31) == 0) {
            int ch = w * 32 + (r & 3) + 8 * (r >> 2) + 4 * q;
            atomicAdd(&st2[ch], s);
            atomicAdd(&st2[128 + ch], sq);
        }
    }
}

// ---- Kernel 4 (MFMA): y3 = bf16(y2f @ W3) [P,256]; bn3 stats ----
// 512 blocks x 8 tiles of 32 pts. Full W3F (exactly 64KB) in LDS.
__global__ __launch_bounds__(256, 2) void k_lin3(
    const unsigned short* __restrict__ y2f, const uint4* __restrict__ W3F,
    unsigned short* __restrict__ y3, float* __restrict__ st3)
{
    __shared__ uint4 w3s[4096];        // 64 KB exactly, frag fi=(mt*8+ks)
    const int tid = threadIdx.x, l = tid & 63, w = tid >> 6;
    #pragma unroll
    for (int r = 0; r < 16; ++r) w3s[r * 256 + tid] = W3F[r * 256 + tid];
    __syncthreads();
    const int n = l & 31, q = l >> 5;
    float s_acc[32], q_acc[32];
    #pragma unroll
    for (int r = 0; r < 32; ++r) { s_acc[r] = 0.f; q_acc[r] = 0.f; }

    for (int t = 0; t < 8; ++t) {
        const int p = (blockIdx.x * 8 + t) * 32 + n;
        const unsigned short* yrow = y2f + (size_t)p * 128 + q * 8;
        bf16x8 Bf[8];
        #pragma unroll
        for (int ks = 0; ks < 8; ++ks) {
            union { uint4 u; bf16x8 v; } bv;
            bv.u = *(const uint4*)(yrow + ks * 16);
            Bf[ks] = bv.v;
        }
        f32x16 acc[2];
        #pragma unroll
        for (int i = 0; i < 2; ++i)
            #pragma unroll
            for (int r = 0; r < 16; ++r) acc[i][r] = 0.f;
        #pragma unroll
        for (int ks = 0; ks < 8; ++ks) {
            #pragma unroll
            for (int i = 0; i < 2; ++i) {
                union { uint4 u; bf16x8 v; } av;
                av.u = w3s[((w * 2 + i) * 8 + ks) * 64 + l];
                acc[i] = __builtin_amdgcn_mfma_f32_32x32x16_bf16(av.v, Bf[ks], acc[i], 0, 0, 0);
            }
        }
        #pragma unroll
        for (int i = 0; i < 2; ++i) {
            #pragma unroll
            for (int g = 0; g < 4; ++g) {
                int ch0 = (w * 2 + i) * 32 + 8 * g + 4 * q;
                ushort4 pk;
                pk.x = (unsigned short)f2bf(acc[i][4*g+0]);
                pk.y = (unsigned short)f2bf(acc[i][4*g+1]);
                pk.z = (unsigned short)f2bf(acc[i][4*g+2]);
                pk.w = (unsigned short)f2bf(acc[i][4*g+3]);
                *(ushort4*)(y3 + (size_t)p * 256 + ch0) = pk;
            }
            #pragma unroll
            for (int r = 0; r < 16; ++r) {
                s_acc[i*16+r] += acc[i][r];
                q_acc[i*16+r] += acc[i][r] * acc[i][r];
            }
        }
    }
    #pragma unroll
    for (int i = 0; i < 2; ++i)
        #pragma unroll
        for (int r = 0; r < 16; ++r) {
            float s = s_acc[i*16+r], sq = q_acc[i*16+r];
            #pragma unroll
            for (int off = 16; off > 0; off >>= 1) {
                s  += __shfl_xor(s, off);
                sq += __shfl_xor(sq, off);
            }
            if ((l & 31) == 0) {
                int ch = (w * 2 + i) * 32 + (r & 3) + 8 * (r >> 2) + 4 * q;
                atomicAdd(&st3[ch], s);
                atomicAdd(&st3[256 + ch], sq);
            }
        }
}

// ---- Kernel 5 (MFMA): x4 = y3f @ W4; packed-u64 scatter max ----
// 1024 blocks: ms=blockIdx&3 (M quarter, W-part exactly 64KB in LDS),
// pg=blockIdx>>2 -> 16 tiles of 32 pts. Wave w -> local M-tile w.
__global__ __launch_bounds__(256, 2) void k_scatter(
    const unsigned short* __restrict__ y3f, const uint4* __restrict__ W4F,
    const int* __restrict__ xy, unsigned long long* __restrict__ pool64)
{
    __shared__ uint4 w4s[4096];        // 64 KB exactly
    const int tid = threadIdx.x, l = tid & 63, w = tid >> 6;
    const int ms = blockIdx.x & 3;
    const int pg = blockIdx.x >> 2;
    #pragma unroll
    for (int r = 0; r < 16; ++r)
        w4s[r * 256 + tid] = W4F[ms * 4096 + r * 256 + tid];
    __syncthreads();
    const int n = l & 31, q = l >> 5;

    for (int t = 0; t < 16; ++t) {
        const int p = (pg * 16 + t) * 32 + n;
        const unsigned short* yrow = y3f + (size_t)p * 256 + q * 8;
        bf16x8 Bf[16];
        #pragma unroll
        for (int ks = 0; ks < 16; ++ks) {
            union { uint4 u; bf16x8 v; } bv;
            bv.u = *(const uint4*)(yrow + ks * 16);
            Bf[ks] = bv.v;
        }
        f32x16 acc;
        #pragma unroll
        for (int r = 0; r < 16; ++r) acc[r] = 0.f;
        #pragma unroll
        for (int ks = 0; ks < 16; ++ks) {
            union { uint4 u; bf16x8 v; } av;
            av.u = w4s[(w * 16 + ks) * 64 + l];
            acc = __builtin_amdgcn_mfma_f32_32x32x16_bf16(av.v, Bf[ks], acc, 0, 0, 0);
        }
        int2 xv = *(const int2*)(xy + 2 * p);
        int key = (p >> 16) * HWSZ + xv.x * WGRID + xv.y;
        unsigned long long* kp = pool64 + (size_t)key * 128;
        #pragma unroll
        for (int g = 0; g < 4; ++g) {
            int ch0 = (ms * 4 + w) * 32 + 8 * g + 4 * q;
            unsigned long long v =
                  (unsigned long long)enc16(f2bf(acc[4*g+0]))
                | ((unsigned long long)enc16(f2bf(acc[4*g+1])) << 16)
                | ((unsigned long long)enc16(f2bf(acc[4*g+2])) << 32)
                | ((unsigned long long)enc16(f2bf(acc[4*g+3])) << 48);
            amax4(kp + (ch0 >> 2), v);
        }
    }
}

// ---- Kernel 6 (MFMA): comp = relu(pooled @ Wc); transpose to [B,CMP,H,W] ----
__global__ __launch_bounds__(256, 4) void k_out(
    const unsigned short* __restrict__ pooled, const unsigned* __restrict__ counts,
    const uint4* __restrict__ WcF, float* __restrict__ out)
{
    __shared__ uint4 wcs[2048];        // 32 KB: full WcF
    const int tid = threadIdx.x, l = tid & 63, w = tid >> 6;
    const int sbase = blockIdx.x * 128;
    #pragma unroll
    for (int r = 0; r < 8; ++r) wcs[r * 256 + tid] = WcF[r * 256 + tid];
    __syncthreads();
    const int n = l & 31, q = l >> 5;
    const int s = sbase + w * 32 + n;
    const unsigned short* prow = pooled + (size_t)s * 512 + q * 8;
    f32x16 acc;
    #pragma unroll
    for (int r = 0; r < 16; ++r) acc[r] = 0.f;

    for (int ks = 0; ks < 32; ++ks) {
        uint4 e = *(const uint4*)(prow + ks * 16);
        unsigned eu[4] = {e.x, e.y, e.z, e.w};
        union { bf16x8 v; unsigned u[4]; } bv;
        #pragma unroll
        for (int jj = 0; jj < 4; ++jj) {
            unsigned e0 = eu[jj] & 0xFFFFu, e1 = eu[jj] >> 16;
            unsigned h0 = (e0 & 0x8000u) ? (e0 & 0x7FFFu) : (~e0 & 0xFFFFu);
            unsigned h1 = (e1 & 0x8000u) ? (e1 & 0x7FFFu) : (~e1 & 0xFFFFu);
            bv.u[jj] = h0 | (h1 << 16);
        }
        union { uint4 u; bf16x8 v; } av;
        av.u = wcs[ks * 64 + l];
        acc = __builtin_amdgcn_mfma_f32_32x32x16_bf16(av.v, bv.v, acc, 0, 0, 0);
    }
    const bool occ = counts[s] > 0;
    const int b = s >> 16, hw = s & 65535;
    #pragma unroll
    for (int r = 0; r < 16; ++r) {
        int ch = (r & 3) + 8 * (r >> 2) + 4 * q;
        float x = occ ? fmaxf(acc[r], 0.f) : 0.f;
        out[(size_t)b * (32 * HWSZ) + (size_t)ch * HWSZ + hw] = x;
    }
}

extern "C" void kernel_launch(void* const* d_in, const int* in_sizes, int n_in,
                              void* d_out, int out_size, void* d_ws, size_t ws_size,
                              hipStream_t stream) {
    const float* pt = (const float*)d_in[0];
    const float* g0 = (const float*)d_in[1];
    const float* b0 = (const float*)d_in[2];
    const float* W1 = (const float*)d_in[3];
    const float* g1 = (const float*)d_in[4];
    const float* b1 = (const float*)d_in[5];
    const float* W2 = (const float*)d_in[6];
    const float* g2 = (const float*)d_in[7];
    const float* b2 = (const float*)d_in[8];
    const float* W3 = (const float*)d_in[9];
    const float* g3 = (const float*)d_in[10];
    const float* b3 = (const float*)d_in[11];
    const float* W4 = (const float*)d_in[12];
    const float* Wc = (const float*)d_in[13];
    const int*   xy = (const int*)d_in[14];
    float* out = (float*)d_out;

    char* ws = (char*)d_ws;
    unsigned short*     y3     = (unsigned short*)(ws + OFF_Y3);
    float*              y1     = (float*)(ws + OFF_Y1);
    unsigned short*     y2     = (unsigned short*)(ws + OFF_Y2);
    unsigned long long* pool64 = (unsigned long long*)(ws + OFF_POOL);
    unsigned short*     pool16 = (unsigned short*)(ws + OFF_POOL);
    unsigned*           counts = (unsigned*)(ws + OFF_CNT);
    float*              st     = (float*)(ws + OFF_ST);
    uint4* W3F = (uint4*)(ws + OFF_W3F);
    uint4* W4F = (uint4*)(ws + OFF_W4F);
    uint4* WcF = (uint4*)(ws + OFF_WCF);
    uint4* W2F = (uint4*)(ws + OFF_W2F);
    float* st0 = st;         // 8 + 8
    float* st1 = st + 16;    // 64 + 64
    float* st2 = st + 144;   // 128 + 128
    float* st3 = st + 400;   // 256 + 256

    // zero counts + stats: 524288 + 4096 B = 33024 uint4
    k_zero<<<129, 256, 0, stream>>>((uint4*)(ws + OFF_CNT), 33024);
    // weights -> bf16 frag layout (368 frag-waves = 92 blocks)
    k_prepw<<<92, 256, 0, stream>>>(W2, W3, W4, Wc, W2F, W3F, W4F, WcF);

    k_stats0<<<512, 256, 0, stream>>>(pt, xy, st0, counts);
    k_lin1<<<P_TOT / 64, 256, 0, stream>>>(pt, g0, b0, W1, st0, y1, st1);
    k_lin2<<<512, 256, 0, stream>>>(y1, g1, b1, W2F, st1, y2, st2);
    k_fold<<<8192, 256, 0, stream>>>(y2, g2, b2, st2, 128, 2097152);
    k_lin3<<<512, 256, 0, stream>>>(y2, W3F, y3, st3);
    k_fold<<<16384, 256, 0, stream>>>(y3, g3, b3, st3, 256, 4194304);
    // y1/y2 dead -> zero pooled (0 == encoded -inf): 128 MiB = 8388608 uint4
    k_zero<<<32768, 256, 0, stream>>>((uint4*)(ws + OFF_POOL), 8388608);
    k_scatter<<<1024, 256, 0, stream>>>(y3, W4F, xy, pool64);
    k_out<<<S_TOT / 128, 256, 0, stream>>>(pool16, counts, WcF, out);
}

// Round 7
// 1107.924 us; speedup vs baseline: 2.0260x; 1.2094x over previous
//
#include <hip/hip_runtime.h>
#include <cstdint>
#include <cstddef>

// PPmodel_all_preprocess — MI355X, round 7: sort-based scatter_max, no atomics.
//
// Round-6: k_scatter 448us atomic-traffic-bound (u64 CAS storm: WRITE 522MB vs
// 134MB ideal ~ write-through per atomic; FETCH 459MB incl 4x y3 re-read).
// Fix: counting-sort points by voxel (counts -> 3-kernel scan -> fill), then
// k_smax processes sorted 32-pt windows (+1 overlap tile): MFMA GEMM, then
// shuffle-based segmented suffix-max across lanes, first-point lane does PLAIN
// stores of raw bf16. No atomics, no 128MB pooled zero-init (unoccupied voxels
// gated by counts>0 in k_out; 0xAA poison decodes to finite bf16, never read
// ungated). k_out drops the enc16 decode (pooled is raw bf16 = B-fragment).
//
// Workspace layout (peak ~195.4 MiB):
//   [0, 64MB)        y3   (P x 256 bf16; raw then folded in place)
//   [64MB, 96MB)     y1   (P x 64 f32)     dead after k_lin2
//   [96MB, 128MB)    y2   (P x 128 bf16; raw then folded in place)
//   [64MB, 192MB)    pooled (S x 512 raw bf16) — written only for occupied
//   [192MB,+512KB)   counts | +4KB stats | offs | cur | bsum | pidf | send |
//                    skey | W3F 64KB | W4F 256KB | WcF 32KB | W2F 16KB

#define P_TOT  131072
#define HWSZ   65536
#define WGRID  256
#define S_TOT  131072
#define EPS    1e-5f
#define CNTF   131072.0f

#define OFF_Y3    0ull
#define OFF_Y1    67108864ull
#define OFF_Y2    100663296ull
#define OFF_POOL  67108864ull
#define OFF_CNT   201326592ull
#define OFF_ST    201850880ull
#define OFF_OFFS  201854976ull
#define OFF_CUR   202379264ull
#define OFF_BSUM  202903552ull
#define OFF_PIDF  202907648ull
#define OFF_SEND  203431936ull
#define OFF_SKEY  203956224ull
#define OFF_W3F   204480512ull
#define OFF_W4F   204546048ull
#define OFF_WCF   204808192ull
#define OFF_W2F   204840960ull

typedef __attribute__((ext_vector_type(8)))  short bf16x8;
typedef __attribute__((ext_vector_type(16))) float f32x16;

// ---- bf16 helpers (manual, RNE) ----
__device__ __forceinline__ unsigned f2bf(float f) {
    unsigned u = __float_as_uint(f);
    return (u + 0x7FFFu + ((u >> 16) & 1u)) >> 16;   // RNE, finite inputs
}
__device__ __forceinline__ float bf2f(unsigned h) {
    return __uint_as_float(h << 16);
}

// ---- zero-fill (graph-capture-safe memset replacement) ----
__global__ __launch_bounds__(256) void k_zero(uint4* __restrict__ p, int n_u4) {
    int i = blockIdx.x * blockDim.x + threadIdx.x;
    if (i < n_u4) p[i] = make_uint4(0u, 0u, 0u, 0u);
}

// ---- Prep: W2/W3/W4/Wc -> bf16 frag layout (A operand, 32x32x16) ----
__global__ __launch_bounds__(256) void k_prepw(
    const float* __restrict__ W2, const float* __restrict__ W3,
    const float* __restrict__ W4, const float* __restrict__ Wc,
    uint4* __restrict__ W2F, uint4* __restrict__ W3F,
    uint4* __restrict__ W4F, uint4* __restrict__ WcF)
{
    int gw = (blockIdx.x * 256 + threadIdx.x) >> 6;
    int l = threadIdx.x & 63;
    const float* W; uint4* dst; int M, mt, ks, fi;
    if (gw < 64)       { fi = gw;       W = W3; dst = W3F; M = 256; mt = fi >> 3; ks = fi & 7;  }
    else if (gw < 320) { fi = gw - 64;  W = W4; dst = W4F; M = 512; mt = fi >> 4; ks = fi & 15; }
    else if (gw < 352) { fi = gw - 320; W = Wc; dst = WcF; M = 32;  mt = 0;      ks = fi;      }
    else               { fi = gw - 352; W = W2; dst = W2F; M = 128; mt = fi >> 2; ks = fi & 3;  }
    int m = mt * 32 + (l & 31);
    int k0 = ks * 16 + (l >> 5) * 8;
    unsigned p[4];
    #pragma unroll
    for (int jj = 0; jj < 4; ++jj) {
        unsigned lo = f2bf(W[(size_t)(k0 + 2*jj)     * M + m]);
        unsigned hi = f2bf(W[(size_t)(k0 + 2*jj + 1) * M + m]);
        p[jj] = lo | (hi << 16);
    }
    dst[(size_t)fi * 64 + l] = make_uint4(p[0], p[1], p[2], p[3]);
}

// ---- In-place fold: y = bf16(relu(bn(y))) for bf16 buffer, nch pow2 ----
__global__ __launch_bounds__(256) void k_fold(
    unsigned short* __restrict__ y, const float* __restrict__ g,
    const float* __restrict__ b, const float* __restrict__ st,
    int nch, int n_u4)
{
    int i = blockIdx.x * 256 + threadIdx.x;
    if (i >= n_u4) return;
    int ch0 = (i * 8) & (nch - 1);
    uint4 e = ((const uint4*)y)[i];
    unsigned eu[4] = {e.x, e.y, e.z, e.w};
    unsigned ou[4];
    #pragma unroll
    for (int jj = 0; jj < 4; ++jj) {
        unsigned r01 = 0;
        #pragma unroll
        for (int hh = 0; hh < 2; ++hh) {
            int c = ch0 + 2*jj + hh;
            float mu = st[c] * (1.0f / CNTF);
            float var = st[nch + c] * (1.0f / CNTF) - mu * mu;
            float rs = rsqrtf(var + EPS);
            float sc = rs * g[c];
            float sh = b[c] - mu * sc;
            unsigned hb = (eu[jj] >> (16 * hh)) & 0xFFFFu;
            float x = fmaxf(fmaf(bf2f(hb), sc, sh), 0.f);
            r01 |= f2bf(x) << (16 * hh);
        }
        ou[jj] = r01;
    }
    ((uint4*)y)[i] = make_uint4(ou[0], ou[1], ou[2], ou[3]);
}

// ---- Kernel 1: bn0 raw stats + per-voxel point counts ----
__global__ __launch_bounds__(256) void k_stats0(
    const float* __restrict__ pt, const int* __restrict__ xy,
    float* __restrict__ st0, unsigned* __restrict__ counts)
{
    int tid = blockIdx.x * blockDim.x + threadIdx.x;
    int stride = gridDim.x * blockDim.x;
    float s[8] = {0,0,0,0,0,0,0,0}, q[8] = {0,0,0,0,0,0,0,0};
    for (int p = tid; p < P_TOT; p += stride) {
        const float4* f4 = (const float4*)(pt + (size_t)p * 8);
        float4 a = f4[0], b = f4[1];
        float v[8] = {a.x,a.y,a.z,a.w,b.x,b.y,b.z,b.w};
        #pragma unroll
        for (int k = 0; k < 8; ++k) { s[k] += v[k]; q[k] += v[k]*v[k]; }
        int key = (p >> 16) * HWSZ + xy[2*p] * WGRID + xy[2*p + 1];
        atomicAdd(&counts[key], 1u);
    }
    #pragma unroll
    for (int k = 0; k < 8; ++k) {
        #pragma unroll
        for (int off = 32; off > 0; off >>= 1) {
            s[k] += __shfl_down(s[k], off);
            q[k] += __shfl_down(q[k], off);
        }
    }
    if ((threadIdx.x & 63) == 0) {
        #pragma unroll
        for (int k = 0; k < 8; ++k) {
            atomicAdd(&st0[k], s[k]);
            atomicAdd(&st0[8 + k], q[k]);
        }
    }
}

// ---- Scan kernels: counts -> exclusive offsets (counting sort phase 1) ----
__global__ __launch_bounds__(256) void k_scan1(
    const unsigned* __restrict__ counts, unsigned* __restrict__ bsum)
{
    __shared__ unsigned sh[256];
    int t = threadIdx.x;
    sh[t] = counts[blockIdx.x * 256 + t];
    __syncthreads();
    for (int d = 128; d > 0; d >>= 1) {
        if (t < d) sh[t] += sh[t + d];
        __syncthreads();
    }
    if (t == 0) bsum[blockIdx.x] = sh[0];
}

__global__ __launch_bounds__(256) void k_scan2(
    const unsigned* __restrict__ bsum, unsigned* __restrict__ boff)
{
    __shared__ unsigned sh[256];
    int t = threadIdx.x;
    unsigned a = bsum[2*t], b = bsum[2*t+1];
    unsigned s = a + b;
    sh[t] = s; __syncthreads();
    for (int d = 1; d < 256; d <<= 1) {
        unsigned u = (t >= d) ? sh[t-d] : 0u;
        __syncthreads();
        sh[t] += u;
        __syncthreads();
    }
    unsigned excl = sh[t] - s;
    boff[2*t]   = excl;
    boff[2*t+1] = excl + a;
}

__global__ __launch_bounds__(256) void k_scan3(
    const unsigned* __restrict__ counts, const unsigned* __restrict__ boff,
    unsigned* __restrict__ offs)
{
    __shared__ unsigned sh[256];
    int t = threadIdx.x, b = blockIdx.x;
    unsigned v = counts[b*256 + t];
    sh[t] = v; __syncthreads();
    for (int d = 1; d < 256; d <<= 1) {
        unsigned u = (t >= d) ? sh[t-d] : 0u;
        __syncthreads();
        sh[t] += u;
        __syncthreads();
    }
    offs[b*256 + t] = boff[b] + sh[t] - v;
}

// ---- Fill: bucket points by voxel (counting sort phase 2) ----
__global__ __launch_bounds__(256) void k_fill(
    const int* __restrict__ xy, const unsigned* __restrict__ offs,
    const unsigned* __restrict__ counts, unsigned* __restrict__ cur,
    unsigned* __restrict__ pidf, unsigned* __restrict__ send,
    unsigned* __restrict__ skey)
{
    int p = blockIdx.x * 256 + threadIdx.x;
    int key = (p >> 16) * HWSZ + xy[2*p] * WGRID + xy[2*p + 1];
    unsigned o = offs[key];
    unsigned r = atomicAdd(&cur[key], 1u);
    unsigned slot = o + r;
    pidf[slot] = (unsigned)p | (r == 0 ? 0x80000000u : 0u);
    send[slot] = o + counts[key];
    skey[slot] = (unsigned)key;
}

// ---- Kernel 2: x0 = bn0(feats); y1 = x0 @ W1 [P,64] f32; bn1 stats ----
__global__ __launch_bounds__(256) void k_lin1(
    const float* __restrict__ pt, const float* __restrict__ g0,
    const float* __restrict__ b0, const float* __restrict__ W1,
    const float* __restrict__ st0, float* __restrict__ y1,
    float* __restrict__ st1)
{
    __shared__ float x0s[64 * 8];
    __shared__ float w1s[8 * 64];
    __shared__ float sc0s[8], sh0s[8];
    __shared__ float red[256];
    const int tid = threadIdx.x;
    const int pbase = blockIdx.x * 64;

    if (tid < 8) {
        float mu = st0[tid] * (1.0f / CNTF);
        float var = st0[8 + tid] * (1.0f / CNTF) - mu * mu;
        float rs = rsqrtf(var + EPS);
        sc0s[tid] = rs * g0[tid];
        sh0s[tid] = b0[tid] - mu * rs * g0[tid];
    }
    __syncthreads();
    if (tid < 128) {
        ((float4*)w1s)[tid] = ((const float4*)W1)[tid];
        float4 f = ((const float4*)(pt + (size_t)pbase * 8))[tid];
        int c = (tid & 1) * 4;
        f.x = fmaf(f.x, sc0s[c + 0], sh0s[c + 0]);
        f.y = fmaf(f.y, sc0s[c + 1], sh0s[c + 1]);
        f.z = fmaf(f.z, sc0s[c + 2], sh0s[c + 2]);
        f.w = fmaf(f.w, sc0s[c + 3], sh0s[c + 3]);
        ((float4*)x0s)[tid] = f;
    }
    __syncthreads();
    const int c = tid & 63;
    const int psub = tid >> 6;
    float ssum = 0.f, ssq = 0.f;
    #pragma unroll
    for (int i = 0; i < 16; ++i) {
        int pl = psub * 16 + i;
        float acc = 0.f;
        #pragma unroll
        for (int k = 0; k < 8; ++k)
            acc = fmaf(x0s[pl * 8 + k], w1s[k * 64 + c], acc);
        y1[(size_t)(pbase + pl) * 64 + c] = acc;
        ssum += acc; ssq += acc * acc;
    }
    red[tid] = ssum; __syncthreads();
    if (tid < 64) atomicAdd(&st1[c], red[c] + red[c+64] + red[c+128] + red[c+192]);
    __syncthreads();
    red[tid] = ssq; __syncthreads();
    if (tid < 64) atomicAdd(&st1[64 + c], red[c] + red[c+64] + red[c+128] + red[c+192]);
}

// ---- Kernel 3 (MFMA): y2 = bf16(relu(bn1(y1)) @ W2) [P,128]; bn2 stats ----
__global__ __launch_bounds__(256, 2) void k_lin2(
    const float* __restrict__ y1, const float* __restrict__ g1,
    const float* __restrict__ b1, const uint4* __restrict__ W2F,
    const float* __restrict__ st1, unsigned short* __restrict__ y2,
    float* __restrict__ st2)
{
    __shared__ uint4 w2s[1024];        // 16 KB
    __shared__ float sc1s[64], sh1s[64];
    const int tid = threadIdx.x, l = tid & 63, w = tid >> 6;
    if (tid < 64) {
        float mu = st1[tid] * (1.0f / CNTF);
        float var = st1[64 + tid] * (1.0f / CNTF) - mu * mu;
        float rs = rsqrtf(var + EPS);
        sc1s[tid] = rs * g1[tid];
        sh1s[tid] = b1[tid] - mu * rs * g1[tid];
    }
    #pragma unroll
    for (int r = 0; r < 4; ++r) w2s[r * 256 + tid] = W2F[r * 256 + tid];
    __syncthreads();
    const int n = l & 31, q = l >> 5;
    float s_acc[16], q_acc[16];
    #pragma unroll
    for (int r = 0; r < 16; ++r) { s_acc[r] = 0.f; q_acc[r] = 0.f; }

    for (int t = 0; t < 8; ++t) {
        const int p = (blockIdx.x * 8 + t) * 32 + n;
        const float* yrow = y1 + (size_t)p * 64 + q * 8;
        bf16x8 Bf[4];
        #pragma unroll
        for (int ks = 0; ks < 4; ++ks) {
            float4 v0 = *(const float4*)(yrow + ks * 16);
            float4 v1 = *(const float4*)(yrow + ks * 16 + 4);
            int k0 = ks * 16 + q * 8;
            float e[8] = {v0.x,v0.y,v0.z,v0.w,v1.x,v1.y,v1.z,v1.w};
            union { bf16x8 v; unsigned u[4]; } cv;
            #pragma unroll
            for (int jj = 0; jj < 4; ++jj) {
                float a0 = fmaxf(fmaf(e[2*jj],   sc1s[k0+2*jj],   sh1s[k0+2*jj]),   0.f);
                float a1 = fmaxf(fmaf(e[2*jj+1], sc1s[k0+2*jj+1], sh1s[k0+2*jj+1]), 0.f);
                cv.u[jj] = f2bf(a0) | (f2bf(a1) << 16);
            }
            Bf[ks] = cv.v;
        }
        f32x16 acc;
        #pragma unroll
        for (int r = 0; r < 16; ++r) acc[r] = 0.f;
        #pragma unroll
        for (int ks = 0; ks < 4; ++ks) {
            union { uint4 u; bf16x8 v; } av;
            av.u = w2s[(w * 4 + ks) * 64 + l];
            acc = __builtin_amdgcn_mfma_f32_32x32x16_bf16(av.v, Bf[ks], acc, 0, 0, 0);
        }
        #pragma unroll
        for (int g = 0; g < 4; ++g) {
            int ch0 = w * 32 + 8 * g + 4 * q;
            ushort4 pk;
            pk.x = (unsigned short)f2bf(acc[4*g+0]);
            pk.y = (unsigned short)f2bf(acc[4*g+1]);
            pk.z = (unsigned short)f2bf(acc[4*g+2]);
            pk.w = (unsigned short)f2bf(acc[4*g+3]);
            *(ushort4*)(y2 + (size_t)p * 128 + ch0) = pk;
        }
        #pragma unroll
        for (int r = 0; r < 16; ++r) { s_acc[r] += acc[r]; q_acc[r] += acc[r]*acc[r]; }
    }
    #pragma unroll
    for (int r = 0; r < 16; ++r) {
        float s = s_acc[r], sq = q_acc[r];
        #pragma unroll
        for (int off = 16; off > 0; off >>= 1) {
            s  += __shfl_xor(s, off);
            sq += __shfl_xor(sq, off);
        }
        if ((l & 31) == 0) {
            int ch = w * 32 + (r & 3) + 8 * (r >> 2) + 4 * q;
            atomicAdd(&st2[ch], s);
            atomicAdd(&st2[128 + ch], sq);
        }
    }
}

// ---- Kernel 4 (MFMA): y3 = bf16(y2f @ W3) [P,256]; bn3 stats ----
__global__ __launch_bounds__(256, 2) void k_lin3(
    const unsigned short* __restrict__ y2f, const uint4* __restrict__ W3F,
    unsigned short* __restrict__ y3, float* __restrict__ st3)
{
    __shared__ uint4 w3s[4096];        // 64 KB
    const int tid = threadIdx.x, l = tid & 63, w = tid >> 6;
    #pragma unroll
    for (int r = 0; r < 16; ++r) w3s[r * 256 + tid] = W3F[r * 256 + tid];
    __syncthreads();
    const int n = l & 31, q = l >> 5;
    float s_acc[32], q_acc[32];
    #pragma unroll
    for (int r = 0; r < 32; ++r) { s_acc[r] = 0.f; q_acc[r] = 0.f; }

    for (int t = 0; t < 8; ++t) {
        const int p = (blockIdx.x * 8 + t) * 32 + n;
        const unsigned short* yrow = y2f + (size_t)p * 128 + q * 8;
        bf16x8 Bf[8];
        #pragma unroll
        for (int ks = 0; ks < 8; ++ks) {
            union { uint4 u; bf16x8 v; } bv;
            bv.u = *(const uint4*)(yrow + ks * 16);
            Bf[ks] = bv.v;
        }
        f32x16 acc[2];
        #pragma unroll
        for (int i = 0; i < 2; ++i)
            #pragma unroll
            for (int r = 0; r < 16; ++r) acc[i][r] = 0.f;
        #pragma unroll
        for (int ks = 0; ks < 8; ++ks) {
            #pragma unroll
            for (int i = 0; i < 2; ++i) {
                union { uint4 u; bf16x8 v; } av;
                av.u = w3s[((w * 2 + i) * 8 + ks) * 64 + l];
                acc[i] = __builtin_amdgcn_mfma_f32_32x32x16_bf16(av.v, Bf[ks], acc[i], 0, 0, 0);
            }
        }
        #pragma unroll
        for (int i = 0; i < 2; ++i) {
            #pragma unroll
            for (int g = 0; g < 4; ++g) {
                int ch0 = (w * 2 + i) * 32 + 8 * g + 4 * q;
                ushort4 pk;
                pk.x = (unsigned short)f2bf(acc[i][4*g+0]);
                pk.y = (unsigned short)f2bf(acc[i][4*g+1]);
                pk.z = (unsigned short)f2bf(acc[i][4*g+2]);
                pk.w = (unsigned short)f2bf(acc[i][4*g+3]);
                *(ushort4*)(y3 + (size_t)p * 256 + ch0) = pk;
            }
            #pragma unroll
            for (int r = 0; r < 16; ++r) {
                s_acc[i*16+r] += acc[i][r];
                q_acc[i*16+r] += acc[i][r] * acc[i][r];
            }
        }
    }
    #pragma unroll
    for (int i = 0; i < 2; ++i)
        #pragma unroll
        for (int r = 0; r < 16; ++r) {
            float s = s_acc[i*16+r], sq = q_acc[i*16+r];
            #pragma unroll
            for (int off = 16; off > 0; off >>= 1) {
                s  += __shfl_xor(s, off);
                sq += __shfl_xor(sq, off);
            }
            if ((l & 31) == 0) {
                int ch = (w * 2 + i) * 32 + (r & 3) + 8 * (r >> 2) + 4 * q;
                atomicAdd(&st3[ch], s);
                atomicAdd(&st3[256 + ch], sq);
            }
        }
}

// ---- Kernel 5 (MFMA): sorted-window GEMM + segmented max + plain stores ----
// blocks = 4 ms-quarters x 512 window-groups (8 windows + 1 overlap tile).
__device__ __forceinline__ void tile_compute(
    int tau, int n, int q, const uint4* __restrict__ A,
    const unsigned short* __restrict__ y3f, const unsigned* __restrict__ pidf,
    const unsigned* __restrict__ send, const unsigned* __restrict__ skey,
    f32x16& acc, unsigned& e, unsigned& isf, unsigned& key)
{
    int pos = tau * 32 + n;
    int sp = pos < P_TOT ? pos : P_TOT - 1;
    unsigned pf = pidf[sp];
    e   = send[sp];
    isf = (pf >> 31) & (pos < P_TOT ? 1u : 0u);
    key = skey[sp];
    const unsigned short* row = y3f + (size_t)(pf & 0x7FFFFFFFu) * 256 + q * 8;
    #pragma unroll
    for (int r = 0; r < 16; ++r) acc[r] = 0.f;
    #pragma unroll
    for (int ks = 0; ks < 16; ++ks) {
        union { uint4 u; bf16x8 v; } bv;
        bv.u = *(const uint4*)(row + ks * 16);
        union { uint4 u; bf16x8 v; } av;
        av.u = A[ks];
        acc = __builtin_amdgcn_mfma_f32_32x32x16_bf16(av.v, bv.v, acc, 0, 0, 0);
    }
}

__global__ __launch_bounds__(256, 2) void k_smax(
    const unsigned short* __restrict__ y3f, const uint4* __restrict__ W4F,
    const unsigned* __restrict__ pidf, const unsigned* __restrict__ send,
    const unsigned* __restrict__ skey, unsigned short* __restrict__ pooled)
{
    __shared__ uint4 w4s[4096];        // 64 KB: W4 quarter (128 ch)
    const int tid = threadIdx.x, l = tid & 63, w = tid >> 6;
    const int ms = blockIdx.x & 3;
    const int wg = blockIdx.x >> 2;    // 0..511
    #pragma unroll
    for (int r = 0; r < 16; ++r)
        w4s[r * 256 + tid] = W4F[ms * 4096 + r * 256 + tid];
    __syncthreads();
    const int n = l & 31, q = l >> 5;
    const int mt = ms * 4 + w;         // global M-tile (32 ch)
    uint4 A[16];
    #pragma unroll
    for (int ks = 0; ks < 16; ++ks) A[ks] = w4s[(w * 16 + ks) * 64 + l];

    const int tau0 = wg * 8;
    f32x16 accP, accC;
    unsigned eP, fP, kP, eC, fC, kC;
    tile_compute(tau0, n, q, A, y3f, pidf, send, skey, accP, eP, fP, kP);

    for (int t = 0; t < 8; ++t) {
        const int tau = tau0 + t;
        tile_compute(tau + 1, n, q, A, y3f, pidf, send, skey, accC, eC, fC, kC);
        // segmented suffix max over positions [32*tau, 32*tau+64)
        f32x16 v1 = accC;              // scan copy (accC must survive)
        const int p0 = tau * 32 + n;
        const int base = q << 5;
        #pragma unroll
        for (int d = 1; d <= 16; d <<= 1) {
            int idx = base | ((n + d) & 31);
            bool sel0 = (n + d) < 32;
            bool c0 = (unsigned)(p0 + d) < eP;
            bool c1 = ((unsigned)(p0 + 32 + d) < eC) && sel0;
            #pragma unroll
            for (int r = 0; r < 16; ++r) {
                float t0 = __shfl(accP[r], idx);
                float t1 = __shfl(v1[r],  idx);
                float part = sel0 ? t0 : t1;
                if (c0) accP[r] = fmaxf(accP[r], part);
                if (c1) v1[r]   = fmaxf(v1[r],  t1);
            }
        }
        if (fP) {
            unsigned short* dst = pooled + (size_t)kP * 512 + mt * 32;
            #pragma unroll
            for (int g = 0; g < 4; ++g) {
                ushort4 pk;
                pk.x = (unsigned short)f2bf(accP[4*g+0]);
                pk.y = (unsigned short)f2bf(accP[4*g+1]);
                pk.z = (unsigned short)f2bf(accP[4*g+2]);
                pk.w = (unsigned short)f2bf(accP[4*g+3]);
                *(ushort4*)(dst + 8 * g + 4 * q) = pk;
            }
        }
        accP = accC; eP = eC; fP = fC; kP = kC;
    }
}

// ---- Kernel 6 (MFMA): comp = relu(pooled @ Wc); transpose to [B,CMP,H,W] ----
__global__ __launch_bounds__(256, 4) void k_out(
    const unsigned short* __restrict__ pooled, const unsigned* __restrict__ counts,
    const uint4* __restrict__ WcF, float* __restrict__ out)
{
    __shared__ uint4 wcs[2048];        // 32 KB: full WcF
    const int tid = threadIdx.x, l = tid & 63, w = tid >> 6;
    const int sbase = blockIdx.x * 128;
    #pragma unroll
    for (int r = 0; r < 8; ++r) wcs[r * 256 + tid] = WcF[r * 256 + tid];
    __syncthreads();
    const int n = l & 31, q = l >> 5;
    const int s = sbase + w * 32 + n;
    const unsigned short* prow = pooled + (size_t)s * 512 + q * 8;
    f32x16 acc;
    #pragma unroll
    for (int r = 0; r < 16; ++r) acc[r] = 0.f;

    for (int ks = 0; ks < 32; ++ks) {
        union { uint4 u; bf16x8 v; } bv;
        bv.u = *(const uint4*)(prow + ks * 16);   // raw bf16 IS the B frag
        union { uint4 u; bf16x8 v; } av;
        av.u = wcs[ks * 64 + l];
        acc = __builtin_amdgcn_mfma_f32_32x32x16_bf16(av.v, bv.v, acc, 0, 0, 0);
    }
    const bool occ = counts[s] > 0;
    const int b = s >> 16, hw = s & 65535;
    #pragma unroll
    for (int r = 0; r < 16; ++r) {
        int ch = (r & 3) + 8 * (r >> 2) + 4 * q;
        float x = occ ? fmaxf(acc[r], 0.f) : 0.f;
        out[(size_t)b * (32 * HWSZ) + (size_t)ch * HWSZ + hw] = x;
    }
}

extern "C" void kernel_launch(void* const* d_in, const int* in_sizes, int n_in,
                              void* d_out, int out_size, void* d_ws, size_t ws_size,
                              hipStream_t stream) {
    const float* pt = (const float*)d_in[0];
    const float* g0 = (const float*)d_in[1];
    const float* b0 = (const float*)d_in[2];
    const float* W1 = (const float*)d_in[3];
    const float* g1 = (const float*)d_in[4];
    const float* b1 = (const float*)d_in[5];
    const float* W2 = (const float*)d_in[6];
    const float* g2 = (const float*)d_in[7];
    const float* b2 = (const float*)d_in[8];
    const float* W3 = (const float*)d_in[9];
    const float* g3 = (const float*)d_in[10];
    const float* b3 = (const float*)d_in[11];
    const float* W4 = (const float*)d_in[12];
    const float* Wc = (const float*)d_in[13];
    const int*   xy = (const int*)d_in[14];
    float* out = (float*)d_out;

    char* ws = (char*)d_ws;
    unsigned short* y3     = (unsigned short*)(ws + OFF_Y3);
    float*          y1     = (float*)(ws + OFF_Y1);
    unsigned short* y2     = (unsigned short*)(ws + OFF_Y2);
    unsigned short* pool16 = (unsigned short*)(ws + OFF_POOL);
    unsigned*       counts = (unsigned*)(ws + OFF_CNT);
    float*          st     = (float*)(ws + OFF_ST);
    unsigned*       offs   = (unsigned*)(ws + OFF_OFFS);
    unsigned*       cur    = (unsigned*)(ws + OFF_CUR);
    unsigned*       bsum   = (unsigned*)(ws + OFF_BSUM);
    unsigned*       pidf   = (unsigned*)(ws + OFF_PIDF);
    unsigned*       send   = (unsigned*)(ws + OFF_SEND);
    unsigned*       skey   = (unsigned*)(ws + OFF_SKEY);
    uint4* W3F = (uint4*)(ws + OFF_W3F);
    uint4* W4F = (uint4*)(ws + OFF_W4F);
    uint4* WcF = (uint4*)(ws + OFF_WCF);
    uint4* W2F = (uint4*)(ws + OFF_W2F);
    float* st0 = st;         // 8 + 8
    float* st1 = st + 16;    // 64 + 64
    float* st2 = st + 144;   // 128 + 128
    float* st3 = st + 400;   // 256 + 256

    // zero counts+stats (528384 B = 33024 u4) and cursors (512 KB = 32768 u4)
    k_zero<<<129, 256, 0, stream>>>((uint4*)(ws + OFF_CNT), 33024);
    k_zero<<<128, 256, 0, stream>>>((uint4*)(ws + OFF_CUR), 32768);
    // weights -> bf16 frag layout
    k_prepw<<<92, 256, 0, stream>>>(W2, W3, W4, Wc, W2F, W3F, W4F, WcF);

    k_stats0<<<512, 256, 0, stream>>>(pt, xy, st0, counts);
    // counting sort: counts -> offs -> slot fill
    k_scan1<<<512, 256, 0, stream>>>(counts, bsum);
    k_scan2<<<1,   256, 0, stream>>>(bsum, bsum + 512);
    k_scan3<<<512, 256, 0, stream>>>(counts, bsum + 512, offs);
    k_fill<<<512, 256, 0, stream>>>(xy, offs, counts, cur, pidf, send, skey);

    k_lin1<<<P_TOT / 64, 256, 0, stream>>>(pt, g0, b0, W1, st0, y1, st1);
    k_lin2<<<512, 256, 0, stream>>>(y1, g1, b1, W2F, st1, y2, st2);
    k_fold<<<8192, 256, 0, stream>>>(y2, g2, b2, st2, 128, 2097152);
    k_lin3<<<512, 256, 0, stream>>>(y2, W3F, y3, st3);
    k_fold<<<16384, 256, 0, stream>>>(y3, g3, b3, st3, 256, 4194304);

    k_smax<<<2048, 256, 0, stream>>>(y3, W4F, pidf, send, skey, pool16);
    k_out<<<S_TOT / 128, 256, 0, stream>>>(pool16, counts, WcF, out);
}

// Round 8
// 652.833 us; speedup vs baseline: 3.4383x; 1.6971x over previous
//
#include <hip/hip_runtime.h>
#include <cstdint>
#include <cstddef>

// PPmodel_all_preprocess — MI355X, round 8: kill same-cache-line atomics.
//
// Round-7: k_stats0 421us with VALUBusy 0.24% = 32768 float atomicAdds onto
// 16 consecutive floats (ONE 64B L2 line) serialized at ~13ns each (the
// arithmetic matches exactly). Hidden since round 3 under bigger kernels
// (top-5 table = 5 replays of the same kernel). k_lin1 has the same disease
// (262144 atomics onto 8 lines). Fixes:
//  * all stats arrays padded to one 64B line per entry (st[i*16])
//  * k_stats0: wave shuffle -> LDS partials -> 16 atomics per BLOCK
//  * k_lin1: 512 blocks x 4 tiles, stats accumulated in regs across tiles
//
// Workspace layout (peak ~195.4 MiB):
//   [0, 64MB)        y3   (P x 256 bf16; raw then folded in place)
//   [64MB, 96MB)     y1   (P x 64 f32)     dead after k_lin2
//   [96MB, 128MB)    y2   (P x 128 bf16; raw then folded in place)
//   [64MB, 192MB)    pooled (S x 512 raw bf16) — written only for occupied
//   [192MB...]       counts | stats(padded x16) | offs | cur | bsum |
//                    pidf | send | skey | W3F | W4F | WcF | W2F

#define P_TOT  131072
#define HWSZ   65536
#define WGRID  256
#define S_TOT  131072
#define EPS    1e-5f
#define CNTF   131072.0f

#define OFF_Y3    0ull
#define OFF_Y1    67108864ull
#define OFF_Y2    100663296ull
#define OFF_POOL  67108864ull
#define OFF_CNT   201326592ull
#define OFF_ST    201850880ull      // 65536 B (14592 floats padded)
#define OFF_OFFS  201916416ull
#define OFF_CUR   202440704ull
#define OFF_BSUM  202964992ull
#define OFF_PIDF  202969088ull
#define OFF_SEND  203493376ull
#define OFF_SKEY  204017664ull
#define OFF_W3F   204541952ull
#define OFF_W4F   204607488ull
#define OFF_WCF   204869632ull
#define OFF_W2F   204902400ull

typedef __attribute__((ext_vector_type(8)))  short bf16x8;
typedef __attribute__((ext_vector_type(16))) float f32x16;

// ---- bf16 helpers (manual, RNE) ----
__device__ __forceinline__ unsigned f2bf(float f) {
    unsigned u = __float_as_uint(f);
    return (u + 0x7FFFu + ((u >> 16) & 1u)) >> 16;   // RNE, finite inputs
}
__device__ __forceinline__ float bf2f(unsigned h) {
    return __uint_as_float(h << 16);
}

// ---- zero-fill (graph-capture-safe memset replacement) ----
__global__ __launch_bounds__(256) void k_zero(uint4* __restrict__ p, int n_u4) {
    int i = blockIdx.x * blockDim.x + threadIdx.x;
    if (i < n_u4) p[i] = make_uint4(0u, 0u, 0u, 0u);
}

// ---- Prep: W2/W3/W4/Wc -> bf16 frag layout (A operand, 32x32x16) ----
__global__ __launch_bounds__(256) void k_prepw(
    const float* __restrict__ W2, const float* __restrict__ W3,
    const float* __restrict__ W4, const float* __restrict__ Wc,
    uint4* __restrict__ W2F, uint4* __restrict__ W3F,
    uint4* __restrict__ W4F, uint4* __restrict__ WcF)
{
    int gw = (blockIdx.x * 256 + threadIdx.x) >> 6;
    int l = threadIdx.x & 63;
    const float* W; uint4* dst; int M, mt, ks, fi;
    if (gw < 64)       { fi = gw;       W = W3; dst = W3F; M = 256; mt = fi >> 3; ks = fi & 7;  }
    else if (gw < 320) { fi = gw - 64;  W = W4; dst = W4F; M = 512; mt = fi >> 4; ks = fi & 15; }
    else if (gw < 352) { fi = gw - 320; W = Wc; dst = WcF; M = 32;  mt = 0;      ks = fi;      }
    else               { fi = gw - 352; W = W2; dst = W2F; M = 128; mt = fi >> 2; ks = fi & 3;  }
    int m = mt * 32 + (l & 31);
    int k0 = ks * 16 + (l >> 5) * 8;
    unsigned p[4];
    #pragma unroll
    for (int jj = 0; jj < 4; ++jj) {
        unsigned lo = f2bf(W[(size_t)(k0 + 2*jj)     * M + m]);
        unsigned hi = f2bf(W[(size_t)(k0 + 2*jj + 1) * M + m]);
        p[jj] = lo | (hi << 16);
    }
    dst[(size_t)fi * 64 + l] = make_uint4(p[0], p[1], p[2], p[3]);
}

// ---- In-place fold: y = bf16(relu(bn(y))); stats padded x16 ----
__global__ __launch_bounds__(256) void k_fold(
    unsigned short* __restrict__ y, const float* __restrict__ g,
    const float* __restrict__ b, const float* __restrict__ st,
    int nch, int n_u4)
{
    int i = blockIdx.x * 256 + threadIdx.x;
    if (i >= n_u4) return;
    int ch0 = (i * 8) & (nch - 1);
    uint4 e = ((const uint4*)y)[i];
    unsigned eu[4] = {e.x, e.y, e.z, e.w};
    unsigned ou[4];
    #pragma unroll
    for (int jj = 0; jj < 4; ++jj) {
        unsigned r01 = 0;
        #pragma unroll
        for (int hh = 0; hh < 2; ++hh) {
            int c = ch0 + 2*jj + hh;
            float mu = st[c * 16] * (1.0f / CNTF);
            float var = st[(nch + c) * 16] * (1.0f / CNTF) - mu * mu;
            float rs = rsqrtf(var + EPS);
            float sc = rs * g[c];
            float sh = b[c] - mu * sc;
            unsigned hb = (eu[jj] >> (16 * hh)) & 0xFFFFu;
            float x = fmaxf(fmaf(bf2f(hb), sc, sh), 0.f);
            r01 |= f2bf(x) << (16 * hh);
        }
        ou[jj] = r01;
    }
    ((uint4*)y)[i] = make_uint4(ou[0], ou[1], ou[2], ou[3]);
}

// ---- Kernel 1: bn0 raw stats (block-reduced) + per-voxel point counts ----
__global__ __launch_bounds__(256) void k_stats0(
    const float* __restrict__ pt, const int* __restrict__ xy,
    float* __restrict__ st0, unsigned* __restrict__ counts)
{
    __shared__ float part[4][16];
    const int tid = threadIdx.x;
    const int p = blockIdx.x * 256 + tid;
    const float4* f4 = (const float4*)(pt + (size_t)p * 8);
    float4 a = f4[0], b = f4[1];
    float v[8] = {a.x,a.y,a.z,a.w,b.x,b.y,b.z,b.w};
    int key = (p >> 16) * HWSZ + xy[2*p] * WGRID + xy[2*p + 1];
    atomicAdd(&counts[key], 1u);
    float s[8], q[8];
    #pragma unroll
    for (int k = 0; k < 8; ++k) { s[k] = v[k]; q[k] = v[k]*v[k]; }
    #pragma unroll
    for (int k = 0; k < 8; ++k) {
        #pragma unroll
        for (int off = 32; off > 0; off >>= 1) {
            s[k] += __shfl_down(s[k], off);
            q[k] += __shfl_down(q[k], off);
        }
    }
    if ((tid & 63) == 0) {
        int w = tid >> 6;
        #pragma unroll
        for (int k = 0; k < 8; ++k) { part[w][k] = s[k]; part[w][8 + k] = q[k]; }
    }
    __syncthreads();
    if (tid < 16) {
        float t = part[0][tid] + part[1][tid] + part[2][tid] + part[3][tid];
        atomicAdd(&st0[tid * 16], t);   // padded: one line per entry
    }
}

// ---- Kernel 2: x0 = bn0(feats); y1 = x0 @ W1 [P,64] f32; bn1 stats ----
// 512 blocks x 4 tiles of 64 pts; stats accumulated in regs across tiles.
__global__ __launch_bounds__(256) void k_lin1(
    const float* __restrict__ pt, const float* __restrict__ g0,
    const float* __restrict__ b0, const float* __restrict__ W1,
    const float* __restrict__ st0, float* __restrict__ y1,
    float* __restrict__ st1)
{
    __shared__ float x0s[64 * 8];
    __shared__ float w1s[8 * 64];
    __shared__ float sc0s[8], sh0s[8];
    __shared__ float red[256];
    const int tid = threadIdx.x;

    if (tid < 8) {
        float mu = st0[tid * 16] * (1.0f / CNTF);
        float var = st0[(8 + tid) * 16] * (1.0f / CNTF) - mu * mu;
        float rs = rsqrtf(var + EPS);
        sc0s[tid] = rs * g0[tid];
        sh0s[tid] = b0[tid] - mu * rs * g0[tid];
    }
    if (tid < 128) ((float4*)w1s)[tid] = ((const float4*)W1)[tid];
    const int c = tid & 63;
    const int psub = tid >> 6;
    float ssum = 0.f, ssq = 0.f;
    for (int t = 0; t < 4; ++t) {
        const int pbase = blockIdx.x * 256 + t * 64;
        __syncthreads();                 // prior tile's x0s readers done
        if (tid < 128) {
            float4 f = ((const float4*)(pt + (size_t)pbase * 8))[tid];
            int cc = (tid & 1) * 4;
            f.x = fmaf(f.x, sc0s[cc + 0], sh0s[cc + 0]);
            f.y = fmaf(f.y, sc0s[cc + 1], sh0s[cc + 1]);
            f.z = fmaf(f.z, sc0s[cc + 2], sh0s[cc + 2]);
            f.w = fmaf(f.w, sc0s[cc + 3], sh0s[cc + 3]);
            ((float4*)x0s)[tid] = f;
        }
        __syncthreads();
        #pragma unroll
        for (int i = 0; i < 16; ++i) {
            int pl = psub * 16 + i;
            float acc = 0.f;
            #pragma unroll
            for (int k = 0; k < 8; ++k)
                acc = fmaf(x0s[pl * 8 + k], w1s[k * 64 + c], acc);
            y1[(size_t)(pbase + pl) * 64 + c] = acc;
            ssum += acc; ssq += acc * acc;
        }
    }
    red[tid] = ssum; __syncthreads();
    if (tid < 64) atomicAdd(&st1[tid * 16],
        red[tid] + red[tid+64] + red[tid+128] + red[tid+192]);
    __syncthreads();
    red[tid] = ssq; __syncthreads();
    if (tid < 64) atomicAdd(&st1[(64 + tid) * 16],
        red[tid] + red[tid+64] + red[tid+128] + red[tid+192]);
}

// ---- Scan kernels: counts -> exclusive offsets (counting sort phase 1) ----
__global__ __launch_bounds__(256) void k_scan1(
    const unsigned* __restrict__ counts, unsigned* __restrict__ bsum)
{
    __shared__ unsigned sh[256];
    int t = threadIdx.x;
    sh[t] = counts[blockIdx.x * 256 + t];
    __syncthreads();
    for (int d = 128; d > 0; d >>= 1) {
        if (t < d) sh[t] += sh[t + d];
        __syncthreads();
    }
    if (t == 0) bsum[blockIdx.x] = sh[0];
}

__global__ __launch_bounds__(256) void k_scan2(
    const unsigned* __restrict__ bsum, unsigned* __restrict__ boff)
{
    __shared__ unsigned sh[256];
    int t = threadIdx.x;
    unsigned a = bsum[2*t], b = bsum[2*t+1];
    unsigned s = a + b;
    sh[t] = s; __syncthreads();
    for (int d = 1; d < 256; d <<= 1) {
        unsigned u = (t >= d) ? sh[t-d] : 0u;
        __syncthreads();
        sh[t] += u;
        __syncthreads();
    }
    unsigned excl = sh[t] - s;
    boff[2*t]   = excl;
    boff[2*t+1] = excl + a;
}

__global__ __launch_bounds__(256) void k_scan3(
    const unsigned* __restrict__ counts, const unsigned* __restrict__ boff,
    unsigned* __restrict__ offs)
{
    __shared__ unsigned sh[256];
    int t = threadIdx.x, b = blockIdx.x;
    unsigned v = counts[b*256 + t];
    sh[t] = v; __syncthreads();
    for (int d = 1; d < 256; d <<= 1) {
        unsigned u = (t >= d) ? sh[t-d] : 0u;
        __syncthreads();
        sh[t] += u;
        __syncthreads();
    }
    offs[b*256 + t] = boff[b] + sh[t] - v;
}

// ---- Fill: bucket points by voxel (counting sort phase 2) ----
__global__ __launch_bounds__(256) void k_fill(
    const int* __restrict__ xy, const unsigned* __restrict__ offs,
    const unsigned* __restrict__ counts, unsigned* __restrict__ cur,
    unsigned* __restrict__ pidf, unsigned* __restrict__ send,
    unsigned* __restrict__ skey)
{
    int p = blockIdx.x * 256 + threadIdx.x;
    int key = (p >> 16) * HWSZ + xy[2*p] * WGRID + xy[2*p + 1];
    unsigned o = offs[key];
    unsigned r = atomicAdd(&cur[key], 1u);
    unsigned slot = o + r;
    pidf[slot] = (unsigned)p | (r == 0 ? 0x80000000u : 0u);
    send[slot] = o + counts[key];
    skey[slot] = (unsigned)key;
}

// ---- Kernel 3 (MFMA): y2 = bf16(relu(bn1(y1)) @ W2) [P,128]; bn2 stats ----
__global__ __launch_bounds__(256, 2) void k_lin2(
    const float* __restrict__ y1, const float* __restrict__ g1,
    const float* __restrict__ b1, const uint4* __restrict__ W2F,
    const float* __restrict__ st1, unsigned short* __restrict__ y2,
    float* __restrict__ st2)
{
    __shared__ uint4 w2s[1024];        // 16 KB
    __shared__ float sc1s[64], sh1s[64];
    const int tid = threadIdx.x, l = tid & 63, w = tid >> 6;
    if (tid < 64) {
        float mu = st1[tid * 16] * (1.0f / CNTF);
        float var = st1[(64 + tid) * 16] * (1.0f / CNTF) - mu * mu;
        float rs = rsqrtf(var + EPS);
        sc1s[tid] = rs * g1[tid];
        sh1s[tid] = b1[tid] - mu * rs * g1[tid];
    }
    #pragma unroll
    for (int r = 0; r < 4; ++r) w2s[r * 256 + tid] = W2F[r * 256 + tid];
    __syncthreads();
    const int n = l & 31, q = l >> 5;
    float s_acc[16], q_acc[16];
    #pragma unroll
    for (int r = 0; r < 16; ++r) { s_acc[r] = 0.f; q_acc[r] = 0.f; }

    for (int t = 0; t < 8; ++t) {
        const int p = (blockIdx.x * 8 + t) * 32 + n;
        const float* yrow = y1 + (size_t)p * 64 + q * 8;
        bf16x8 Bf[4];
        #pragma unroll
        for (int ks = 0; ks < 4; ++ks) {
            float4 v0 = *(const float4*)(yrow + ks * 16);
            float4 v1 = *(const float4*)(yrow + ks * 16 + 4);
            int k0 = ks * 16 + q * 8;
            float e[8] = {v0.x,v0.y,v0.z,v0.w,v1.x,v1.y,v1.z,v1.w};
            union { bf16x8 v; unsigned u[4]; } cv;
            #pragma unroll
            for (int jj = 0; jj < 4; ++jj) {
                float a0 = fmaxf(fmaf(e[2*jj],   sc1s[k0+2*jj],   sh1s[k0+2*jj]),   0.f);
                float a1 = fmaxf(fmaf(e[2*jj+1], sc1s[k0+2*jj+1], sh1s[k0+2*jj+1]), 0.f);
                cv.u[jj] = f2bf(a0) | (f2bf(a1) << 16);
            }
            Bf[ks] = cv.v;
        }
        f32x16 acc;
        #pragma unroll
        for (int r = 0; r < 16; ++r) acc[r] = 0.f;
        #pragma unroll
        for (int ks = 0; ks < 4; ++ks) {
            union { uint4 u; bf16x8 v; } av;
            av.u = w2s[(w * 4 + ks) * 64 + l];
            acc = __builtin_amdgcn_mfma_f32_32x32x16_bf16(av.v, Bf[ks], acc, 0, 0, 0);
        }
        #pragma unroll
        for (int g = 0; g < 4; ++g) {
            int ch0 = w * 32 + 8 * g + 4 * q;
            ushort4 pk;
            pk.x = (unsigned short)f2bf(acc[4*g+0]);
            pk.y = (unsigned short)f2bf(acc[4*g+1]);
            pk.z = (unsigned short)f2bf(acc[4*g+2]);
            pk.w = (unsigned short)f2bf(acc[4*g+3]);
            *(ushort4*)(y2 + (size_t)p * 128 + ch0) = pk;
        }
        #pragma unroll
        for (int r = 0; r < 16; ++r) { s_acc[r] += acc[r]; q_acc[r] += acc[r]*acc[r]; }
    }
    #pragma unroll
    for (int r = 0; r < 16; ++r) {
        float s = s_acc[r], sq = q_acc[r];
        #pragma unroll
        for (int off = 16; off > 0; off >>= 1) {
            s  += __shfl_xor(s, off);
            sq += __shfl_xor(sq, off);
        }
        if ((l & 31) == 0) {
            int ch = w * 32 + (r & 3) + 8 * (r >> 2) + 4 * q;
            atomicAdd(&st2[ch * 16], s);
            atomicAdd(&st2[(128 + ch) * 16], sq);
        }
    }
}

// ---- Kernel 4 (MFMA): y3 = bf16(y2f @ W3) [P,256]; bn3 stats ----
__global__ __launch_bounds__(256, 2) void k_lin3(
    const unsigned short* __restrict__ y2f, const uint4* __restrict__ W3F,
    unsigned short* __restrict__ y3, float* __restrict__ st3)
{
    __shared__ uint4 w3s[4096];        // 64 KB
    const int tid = threadIdx.x, l = tid & 63, w = tid >> 6;
    #pragma unroll
    for (int r = 0; r < 16; ++r) w3s[r * 256 + tid] = W3F[r * 256 + tid];
    __syncthreads();
    const int n = l & 31, q = l >> 5;
    float s_acc[32], q_acc[32];
    #pragma unroll
    for (int r = 0; r < 32; ++r) { s_acc[r] = 0.f; q_acc[r] = 0.f; }

    for (int t = 0; t < 8; ++t) {
        const int p = (blockIdx.x * 8 + t) * 32 + n;
        const unsigned short* yrow = y2f + (size_t)p * 128 + q * 8;
        bf16x8 Bf[8];
        #pragma unroll
        for (int ks = 0; ks < 8; ++ks) {
            union { uint4 u; bf16x8 v; } bv;
            bv.u = *(const uint4*)(yrow + ks * 16);
            Bf[ks] = bv.v;
        }
        f32x16 acc[2];
        #pragma unroll
        for (int i = 0; i < 2; ++i)
            #pragma unroll
            for (int r = 0; r < 16; ++r) acc[i][r] = 0.f;
        #pragma unroll
        for (int ks = 0; ks < 8; ++ks) {
            #pragma unroll
            for (int i = 0; i < 2; ++i) {
                union { uint4 u; bf16x8 v; } av;
                av.u = w3s[((w * 2 + i) * 8 + ks) * 64 + l];
                acc[i] = __builtin_amdgcn_mfma_f32_32x32x16_bf16(av.v, Bf[ks], acc[i], 0, 0, 0);
            }
        }
        #pragma unroll
        for (int i = 0; i < 2; ++i) {
            #pragma unroll
            for (int g = 0; g < 4; ++g) {
                int ch0 = (w * 2 + i) * 32 + 8 * g + 4 * q;
                ushort4 pk;
                pk.x = (unsigned short)f2bf(acc[i][4*g+0]);
                pk.y = (unsigned short)f2bf(acc[i][4*g+1]);
                pk.z = (unsigned short)f2bf(acc[i][4*g+2]);
                pk.w = (unsigned short)f2bf(acc[i][4*g+3]);
                *(ushort4*)(y3 + (size_t)p * 256 + ch0) = pk;
            }
            #pragma unroll
            for (int r = 0; r < 16; ++r) {
                s_acc[i*16+r] += acc[i][r];
                q_acc[i*16+r] += acc[i][r] * acc[i][r];
            }
        }
    }
    #pragma unroll
    for (int i = 0; i < 2; ++i)
        #pragma unroll
        for (int r = 0; r < 16; ++r) {
            float s = s_acc[i*16+r], sq = q_acc[i*16+r];
            #pragma unroll
            for (int off = 16; off > 0; off >>= 1) {
                s  += __shfl_xor(s, off);
                sq += __shfl_xor(sq, off);
            }
            if ((l & 31) == 0) {
                int ch = (w * 2 + i) * 32 + (r & 3) + 8 * (r >> 2) + 4 * q;
                atomicAdd(&st3[ch * 16], s);
                atomicAdd(&st3[(256 + ch) * 16], sq);
            }
        }
}

// ---- Kernel 5 (MFMA): sorted-window GEMM + segmented max + plain stores ----
__device__ __forceinline__ void tile_compute(
    int tau, int n, int q, const uint4* __restrict__ A,
    const unsigned short* __restrict__ y3f, const unsigned* __restrict__ pidf,
    const unsigned* __restrict__ send, const unsigned* __restrict__ skey,
    f32x16& acc, unsigned& e, unsigned& isf, unsigned& key)
{
    int pos = tau * 32 + n;
    int sp = pos < P_TOT ? pos : P_TOT - 1;
    unsigned pf = pidf[sp];
    e   = send[sp];
    isf = (pf >> 31) & (pos < P_TOT ? 1u : 0u);
    key = skey[sp];
    const unsigned short* row = y3f + (size_t)(pf & 0x7FFFFFFFu) * 256 + q * 8;
    #pragma unroll
    for (int r = 0; r < 16; ++r) acc[r] = 0.f;
    #pragma unroll
    for (int ks = 0; ks < 16; ++ks) {
        union { uint4 u; bf16x8 v; } bv;
        bv.u = *(const uint4*)(row + ks * 16);
        union { uint4 u; bf16x8 v; } av;
        av.u = A[ks];
        acc = __builtin_amdgcn_mfma_f32_32x32x16_bf16(av.v, bv.v, acc, 0, 0, 0);
    }
}

__global__ __launch_bounds__(256, 2) void k_smax(
    const unsigned short* __restrict__ y3f, const uint4* __restrict__ W4F,
    const unsigned* __restrict__ pidf, const unsigned* __restrict__ send,
    const unsigned* __restrict__ skey, unsigned short* __restrict__ pooled)
{
    __shared__ uint4 w4s[4096];        // 64 KB: W4 quarter (128 ch)
    const int tid = threadIdx.x, l = tid & 63, w = tid >> 6;
    const int ms = blockIdx.x & 3;
    const int wg = blockIdx.x >> 2;    // 0..511
    #pragma unroll
    for (int r = 0; r < 16; ++r)
        w4s[r * 256 + tid] = W4F[ms * 4096 + r * 256 + tid];
    __syncthreads();
    const int n = l & 31, q = l >> 5;
    const int mt = ms * 4 + w;         // global M-tile (32 ch)
    uint4 A[16];
    #pragma unroll
    for (int ks = 0; ks < 16; ++ks) A[ks] = w4s[(w * 16 + ks) * 64 + l];

    const int tau0 = wg * 8;
    f32x16 accP, accC;
    unsigned eP, fP, kP, eC, fC, kC;
    tile_compute(tau0, n, q, A, y3f, pidf, send, skey, accP, eP, fP, kP);

    for (int t = 0; t < 8; ++t) {
        const int tau = tau0 + t;
        tile_compute(tau + 1, n, q, A, y3f, pidf, send, skey, accC, eC, fC, kC);
        // segmented suffix max over positions [32*tau, 32*tau+64)
        f32x16 v1 = accC;              // scan copy (accC must survive)
        const int p0 = tau * 32 + n;
        const int base = q << 5;
        #pragma unroll
        for (int d = 1; d <= 16; d <<= 1) {
            int idx = base | ((n + d) & 31);
            bool sel0 = (n + d) < 32;
            bool c0 = (unsigned)(p0 + d) < eP;
            bool c1 = ((unsigned)(p0 + 32 + d) < eC) && sel0;
            #pragma unroll
            for (int r = 0; r < 16; ++r) {
                float t0 = __shfl(accP[r], idx);
                float t1 = __shfl(v1[r],  idx);
                float part = sel0 ? t0 : t1;
                if (c0) accP[r] = fmaxf(accP[r], part);
                if (c1) v1[r]   = fmaxf(v1[r],  t1);
            }
        }
        if (fP) {
            unsigned short* dst = pooled + (size_t)kP * 512 + mt * 32;
            #pragma unroll
            for (int g = 0; g < 4; ++g) {
                ushort4 pk;
                pk.x = (unsigned short)f2bf(accP[4*g+0]);
                pk.y = (unsigned short)f2bf(accP[4*g+1]);
                pk.z = (unsigned short)f2bf(accP[4*g+2]);
                pk.w = (unsigned short)f2bf(accP[4*g+3]);
                *(ushort4*)(dst + 8 * g + 4 * q) = pk;
            }
        }
        accP = accC; eP = eC; fP = fC; kP = kC;
    }
}

// ---- Kernel 6 (MFMA): comp = relu(pooled @ Wc); transpose to [B,CMP,H,W] ----
__global__ __launch_bounds__(256, 4) void k_out(
    const unsigned short* __restrict__ pooled, const unsigned* __restrict__ counts,
    const uint4* __restrict__ WcF, float* __restrict__ out)
{
    __shared__ uint4 wcs[2048];        // 32 KB: full WcF
    const int tid = threadIdx.x, l = tid & 63, w = tid >> 6;
    const int sbase = blockIdx.x * 128;
    #pragma unroll
    for (int r = 0; r < 8; ++r) wcs[r * 256 + tid] = WcF[r * 256 + tid];
    __syncthreads();
    const int n = l & 31, q = l >> 5;
    const int s = sbase + w * 32 + n;
    const unsigned short* prow = pooled + (size_t)s * 512 + q * 8;
    f32x16 acc;
    #pragma unroll
    for (int r = 0; r < 16; ++r) acc[r] = 0.f;

    for (int ks = 0; ks < 32; ++ks) {
        union { uint4 u; bf16x8 v; } bv;
        bv.u = *(const uint4*)(prow + ks * 16);   // raw bf16 IS the B frag
        union { uint4 u; bf16x8 v; } av;
        av.u = wcs[ks * 64 + l];
        acc = __builtin_amdgcn_mfma_f32_32x32x16_bf16(av.v, bv.v, acc, 0, 0, 0);
    }
    const bool occ = counts[s] > 0;
    const int b = s >> 16, hw = s & 65535;
    #pragma unroll
    for (int r = 0; r < 16; ++r) {
        int ch = (r & 3) + 8 * (r >> 2) + 4 * q;
        float x = occ ? fmaxf(acc[r], 0.f) : 0.f;
        out[(size_t)b * (32 * HWSZ) + (size_t)ch * HWSZ + hw] = x;
    }
}

extern "C" void kernel_launch(void* const* d_in, const int* in_sizes, int n_in,
                              void* d_out, int out_size, void* d_ws, size_t ws_size,
                              hipStream_t stream) {
    const float* pt = (const float*)d_in[0];
    const float* g0 = (const float*)d_in[1];
    const float* b0 = (const float*)d_in[2];
    const float* W1 = (const float*)d_in[3];
    const float* g1 = (const float*)d_in[4];
    const float* b1 = (const float*)d_in[5];
    const float* W2 = (const float*)d_in[6];
    const float* g2 = (const float*)d_in[7];
    const float* b2 = (const float*)d_in[8];
    const float* W3 = (const float*)d_in[9];
    const float* g3 = (const float*)d_in[10];
    const float* b3 = (const float*)d_in[11];
    const float* W4 = (const float*)d_in[12];
    const float* Wc = (const float*)d_in[13];
    const int*   xy = (const int*)d_in[14];
    float* out = (float*)d_out;

    char* ws = (char*)d_ws;
    unsigned short* y3     = (unsigned short*)(ws + OFF_Y3);
    float*          y1     = (float*)(ws + OFF_Y1);
    unsigned short* y2     = (unsigned short*)(ws + OFF_Y2);
    unsigned short* pool16 = (unsigned short*)(ws + OFF_POOL);
    unsigned*       counts = (unsigned*)(ws + OFF_CNT);
    float*          st     = (float*)(ws + OFF_ST);
    unsigned*       offs   = (unsigned*)(ws + OFF_OFFS);
    unsigned*       cur    = (unsigned*)(ws + OFF_CUR);
    unsigned*       bsum   = (unsigned*)(ws + OFF_BSUM);
    unsigned*       pidf   = (unsigned*)(ws + OFF_PIDF);
    unsigned*       send   = (unsigned*)(ws + OFF_SEND);
    unsigned*       skey   = (unsigned*)(ws + OFF_SKEY);
    uint4* W3F = (uint4*)(ws + OFF_W3F);
    uint4* W4F = (uint4*)(ws + OFF_W4F);
    uint4* WcF = (uint4*)(ws + OFF_WCF);
    uint4* W2F = (uint4*)(ws + OFF_W2F);
    // padded stats: one 64B line per entry (entry i at st[i*16])
    float* st0 = st;            // 16 entries
    float* st1 = st + 256;      // 128 entries
    float* st2 = st + 2304;     // 256 entries
    float* st3 = st + 6400;     // 512 entries

    // zero counts (512KB) + padded stats (64KB) contiguously: 36864 uint4
    k_zero<<<144, 256, 0, stream>>>((uint4*)(ws + OFF_CNT), 36864);
    k_zero<<<128, 256, 0, stream>>>((uint4*)(ws + OFF_CUR), 32768);
    // weights -> bf16 frag layout
    k_prepw<<<92, 256, 0, stream>>>(W2, W3, W4, Wc, W2F, W3F, W4F, WcF);

    k_stats0<<<512, 256, 0, stream>>>(pt, xy, st0, counts);
    // counting sort: counts -> offs -> slot fill
    k_scan1<<<512, 256, 0, stream>>>(counts, bsum);
    k_scan2<<<1,   256, 0, stream>>>(bsum, bsum + 512);
    k_scan3<<<512, 256, 0, stream>>>(counts, bsum + 512, offs);
    k_fill<<<512, 256, 0, stream>>>(xy, offs, counts, cur, pidf, send, skey);

    k_lin1<<<512, 256, 0, stream>>>(pt, g0, b0, W1, st0, y1, st1);
    k_lin2<<<512, 256, 0, stream>>>(y1, g1, b1, W2F, st1, y2, st2);
    k_fold<<<8192, 256, 0, stream>>>(y2, g2, b2, st2, 128, 2097152);
    k_lin3<<<512, 256, 0, stream>>>(y2, W3F, y3, st3);
    k_fold<<<16384, 256, 0, stream>>>(y3, g3, b3, st3, 256, 4194304);

    k_smax<<<2048, 256, 0, stream>>>(y3, W4F, pidf, send, skey, pool16);
    k_out<<<S_TOT / 128, 256, 0, stream>>>(pool16, counts, WcF, out);
}

// Round 9
// 488.774 us; speedup vs baseline: 4.5924x; 1.3357x over previous
//
#include <hip/hip_runtime.h>
#include <cstdint>
#include <cstddef>

// PPmodel_all_preprocess — MI355X, round 9: lane=channel orientation for smax.
//
// Round-8: k_smax 215us, VALU 41% / MFMA 7.5% = the cross-lane segmented scan
// (~160 ds_bpermute/tile vs 128 MFMA cyc). Fix: swap mfma operand order
// (A=X, B=W4) so C has col=lane=CHANNEL, row=reg=POINT. Segmented max is then
// register-local: one 16-op shfl_xor(32) half-exchange + 31-step serial
// suffix-max with WAVE-UNIFORM conditions (v_readlane of segment ends ->
// scalar cmp). A/B frag layouts are mirror images, so W4F and the y3 row
// loads are reused unchanged. W4 frags register-resident from global (no LDS,
// no barriers in k_smax). Windows processed descending with a single carry
// float (max segment ~12 << 32). Also: k_fold's 33M rsqrt -> k_bnprep
// precomputes per-channel (sc,sh); merged zero launches.
//
// Workspace layout (peak ~195.4 MiB): y3 | y1 | y2 | pooled(alias) | counts |
//   stats(padded x16) | offs | cur | bsum | pidf | send | skey | W3F | W4F |
//   WcF | W2F | scsh

#define P_TOT  131072
#define HWSZ   65536
#define WGRID  256
#define S_TOT  131072
#define EPS    1e-5f
#define CNTF   131072.0f

#define OFF_Y3    0ull
#define OFF_Y1    67108864ull
#define OFF_Y2    100663296ull
#define OFF_POOL  67108864ull
#define OFF_CNT   201326592ull
#define OFF_ST    201850880ull
#define OFF_OFFS  201916416ull
#define OFF_CUR   202440704ull
#define OFF_BSUM  202964992ull
#define OFF_PIDF  202969088ull
#define OFF_SEND  203493376ull
#define OFF_SKEY  204017664ull
#define OFF_W3F   204541952ull
#define OFF_W4F   204607488ull
#define OFF_WCF   204869632ull
#define OFF_W2F   204902400ull
#define OFF_SCSH  204918784ull

typedef __attribute__((ext_vector_type(8)))  short bf16x8;
typedef __attribute__((ext_vector_type(16))) float f32x16;

// ---- bf16 helpers (manual, RNE) ----
__device__ __forceinline__ unsigned f2bf(float f) {
    unsigned u = __float_as_uint(f);
    return (u + 0x7FFFu + ((u >> 16) & 1u)) >> 16;   // RNE, finite inputs
}
__device__ __forceinline__ float bf2f(unsigned h) {
    return __uint_as_float(h << 16);
}

// ---- zero-fill (graph-capture-safe memset replacement) ----
__global__ __launch_bounds__(256) void k_zero(uint4* __restrict__ p, int n_u4) {
    int i = blockIdx.x * blockDim.x + threadIdx.x;
    if (i < n_u4) p[i] = make_uint4(0u, 0u, 0u, 0u);
}

// ---- Prep: W2/W3/W4/Wc -> bf16 frag layout (32x32x16 operand) ----
__global__ __launch_bounds__(256) void k_prepw(
    const float* __restrict__ W2, const float* __restrict__ W3,
    const float* __restrict__ W4, const float* __restrict__ Wc,
    uint4* __restrict__ W2F, uint4* __restrict__ W3F,
    uint4* __restrict__ W4F, uint4* __restrict__ WcF)
{
    int gw = (blockIdx.x * 256 + threadIdx.x) >> 6;
    int l = threadIdx.x & 63;
    const float* W; uint4* dst; int M, mt, ks, fi;
    if (gw < 64)       { fi = gw;       W = W3; dst = W3F; M = 256; mt = fi >> 3; ks = fi & 7;  }
    else if (gw < 320) { fi = gw - 64;  W = W4; dst = W4F; M = 512; mt = fi >> 4; ks = fi & 15; }
    else if (gw < 352) { fi = gw - 320; W = Wc; dst = WcF; M = 32;  mt = 0;      ks = fi;      }
    else               { fi = gw - 352; W = W2; dst = W2F; M = 128; mt = fi >> 2; ks = fi & 3;  }
    int m = mt * 32 + (l & 31);
    int k0 = ks * 16 + (l >> 5) * 8;
    unsigned p[4];
    #pragma unroll
    for (int jj = 0; jj < 4; ++jj) {
        unsigned lo = f2bf(W[(size_t)(k0 + 2*jj)     * M + m]);
        unsigned hi = f2bf(W[(size_t)(k0 + 2*jj + 1) * M + m]);
        p[jj] = lo | (hi << 16);
    }
    dst[(size_t)fi * 64 + l] = make_uint4(p[0], p[1], p[2], p[3]);
}

// ---- bn fold coefficients: sc[c] = rs*g, sh[c] = b - mu*sc ----
__global__ __launch_bounds__(256) void k_bnprep(
    const float* __restrict__ st, const float* __restrict__ g,
    const float* __restrict__ b, float* __restrict__ sc,
    float* __restrict__ sh, int nch)
{
    int c = blockIdx.x * 256 + threadIdx.x;
    if (c >= nch) return;
    float mu = st[c * 16] * (1.0f / CNTF);
    float var = st[(nch + c) * 16] * (1.0f / CNTF) - mu * mu;
    float rs = rsqrtf(var + EPS);
    float s = rs * g[c];
    sc[c] = s;
    sh[c] = b[c] - mu * s;
}

// ---- In-place fold: y = bf16(relu(y*sc+sh)) for bf16 buffer, nch pow2 ----
__global__ __launch_bounds__(256) void k_fold(
    unsigned short* __restrict__ y, const float* __restrict__ sc,
    const float* __restrict__ sh, int nch, int n_u4)
{
    int i = blockIdx.x * 256 + threadIdx.x;
    if (i >= n_u4) return;
    int ch0 = (i * 8) & (nch - 1);
    float4 s0 = *(const float4*)(sc + ch0), s1 = *(const float4*)(sc + ch0 + 4);
    float4 h0 = *(const float4*)(sh + ch0), h1 = *(const float4*)(sh + ch0 + 4);
    float scv[8] = {s0.x,s0.y,s0.z,s0.w,s1.x,s1.y,s1.z,s1.w};
    float shv[8] = {h0.x,h0.y,h0.z,h0.w,h1.x,h1.y,h1.z,h1.w};
    uint4 e = ((const uint4*)y)[i];
    unsigned eu[4] = {e.x, e.y, e.z, e.w};
    unsigned ou[4];
    #pragma unroll
    for (int jj = 0; jj < 4; ++jj) {
        float x0 = fmaxf(fmaf(bf2f(eu[jj] & 0xFFFFu), scv[2*jj],   shv[2*jj]),   0.f);
        float x1 = fmaxf(fmaf(bf2f(eu[jj] >> 16),     scv[2*jj+1], shv[2*jj+1]), 0.f);
        ou[jj] = f2bf(x0) | (f2bf(x1) << 16);
    }
    ((uint4*)y)[i] = make_uint4(ou[0], ou[1], ou[2], ou[3]);
}

// ---- Kernel 1: bn0 raw stats (block-reduced) + per-voxel point counts ----
__global__ __launch_bounds__(256) void k_stats0(
    const float* __restrict__ pt, const int* __restrict__ xy,
    float* __restrict__ st0, unsigned* __restrict__ counts)
{
    __shared__ float part[4][16];
    const int tid = threadIdx.x;
    const int p = blockIdx.x * 256 + tid;
    const float4* f4 = (const float4*)(pt + (size_t)p * 8);
    float4 a = f4[0], b = f4[1];
    float v[8] = {a.x,a.y,a.z,a.w,b.x,b.y,b.z,b.w};
    int key = (p >> 16) * HWSZ + xy[2*p] * WGRID + xy[2*p + 1];
    atomicAdd(&counts[key], 1u);
    float s[8], q[8];
    #pragma unroll
    for (int k = 0; k < 8; ++k) { s[k] = v[k]; q[k] = v[k]*v[k]; }
    #pragma unroll
    for (int k = 0; k < 8; ++k) {
        #pragma unroll
        for (int off = 32; off > 0; off >>= 1) {
            s[k] += __shfl_down(s[k], off);
            q[k] += __shfl_down(q[k], off);
        }
    }
    if ((tid & 63) == 0) {
        int w = tid >> 6;
        #pragma unroll
        for (int k = 0; k < 8; ++k) { part[w][k] = s[k]; part[w][8 + k] = q[k]; }
    }
    __syncthreads();
    if (tid < 16) {
        float t = part[0][tid] + part[1][tid] + part[2][tid] + part[3][tid];
        atomicAdd(&st0[tid * 16], t);
    }
}

// ---- Kernel 2: x0 = bn0(feats); y1 = x0 @ W1 [P,64] f32; bn1 stats ----
__global__ __launch_bounds__(256) void k_lin1(
    const float* __restrict__ pt, const float* __restrict__ g0,
    const float* __restrict__ b0, const float* __restrict__ W1,
    const float* __restrict__ st0, float* __restrict__ y1,
    float* __restrict__ st1)
{
    __shared__ float x0s[64 * 8];
    __shared__ float w1s[8 * 64];
    __shared__ float sc0s[8], sh0s[8];
    __shared__ float red[256];
    const int tid = threadIdx.x;

    if (tid < 8) {
        float mu = st0[tid * 16] * (1.0f / CNTF);
        float var = st0[(8 + tid) * 16] * (1.0f / CNTF) - mu * mu;
        float rs = rsqrtf(var + EPS);
        sc0s[tid] = rs * g0[tid];
        sh0s[tid] = b0[tid] - mu * rs * g0[tid];
    }
    if (tid < 128) ((float4*)w1s)[tid] = ((const float4*)W1)[tid];
    const int c = tid & 63;
    const int psub = tid >> 6;
    float ssum = 0.f, ssq = 0.f;
    for (int t = 0; t < 4; ++t) {
        const int pbase = blockIdx.x * 256 + t * 64;
        __syncthreads();
        if (tid < 128) {
            float4 f = ((const float4*)(pt + (size_t)pbase * 8))[tid];
            int cc = (tid & 1) * 4;
            f.x = fmaf(f.x, sc0s[cc + 0], sh0s[cc + 0]);
            f.y = fmaf(f.y, sc0s[cc + 1], sh0s[cc + 1]);
            f.z = fmaf(f.z, sc0s[cc + 2], sh0s[cc + 2]);
            f.w = fmaf(f.w, sc0s[cc + 3], sh0s[cc + 3]);
            ((float4*)x0s)[tid] = f;
        }
        __syncthreads();
        #pragma unroll
        for (int i = 0; i < 16; ++i) {
            int pl = psub * 16 + i;
            float acc = 0.f;
            #pragma unroll
            for (int k = 0; k < 8; ++k)
                acc = fmaf(x0s[pl * 8 + k], w1s[k * 64 + c], acc);
            y1[(size_t)(pbase + pl) * 64 + c] = acc;
            ssum += acc; ssq += acc * acc;
        }
    }
    red[tid] = ssum; __syncthreads();
    if (tid < 64) atomicAdd(&st1[tid * 16],
        red[tid] + red[tid+64] + red[tid+128] + red[tid+192]);
    __syncthreads();
    red[tid] = ssq; __syncthreads();
    if (tid < 64) atomicAdd(&st1[(64 + tid) * 16],
        red[tid] + red[tid+64] + red[tid+128] + red[tid+192]);
}

// ---- Scan kernels: counts -> exclusive offsets ----
__global__ __launch_bounds__(256) void k_scan1(
    const unsigned* __restrict__ counts, unsigned* __restrict__ bsum)
{
    __shared__ unsigned sh[256];
    int t = threadIdx.x;
    sh[t] = counts[blockIdx.x * 256 + t];
    __syncthreads();
    for (int d = 128; d > 0; d >>= 1) {
        if (t < d) sh[t] += sh[t + d];
        __syncthreads();
    }
    if (t == 0) bsum[blockIdx.x] = sh[0];
}

__global__ __launch_bounds__(256) void k_scan2(
    const unsigned* __restrict__ bsum, unsigned* __restrict__ boff)
{
    __shared__ unsigned sh[256];
    int t = threadIdx.x;
    unsigned a = bsum[2*t], b = bsum[2*t+1];
    unsigned s = a + b;
    sh[t] = s; __syncthreads();
    for (int d = 1; d < 256; d <<= 1) {
        unsigned u = (t >= d) ? sh[t-d] : 0u;
        __syncthreads();
        sh[t] += u;
        __syncthreads();
    }
    unsigned excl = sh[t] - s;
    boff[2*t]   = excl;
    boff[2*t+1] = excl + a;
}

__global__ __launch_bounds__(256) void k_scan3(
    const unsigned* __restrict__ counts, const unsigned* __restrict__ boff,
    unsigned* __restrict__ offs)
{
    __shared__ unsigned sh[256];
    int t = threadIdx.x, b = blockIdx.x;
    unsigned v = counts[b*256 + t];
    sh[t] = v; __syncthreads();
    for (int d = 1; d < 256; d <<= 1) {
        unsigned u = (t >= d) ? sh[t-d] : 0u;
        __syncthreads();
        sh[t] += u;
        __syncthreads();
    }
    offs[b*256 + t] = boff[b] + sh[t] - v;
}

// ---- Fill: bucket points by voxel ----
__global__ __launch_bounds__(256) void k_fill(
    const int* __restrict__ xy, const unsigned* __restrict__ offs,
    const unsigned* __restrict__ counts, unsigned* __restrict__ cur,
    unsigned* __restrict__ pidf, unsigned* __restrict__ send,
    unsigned* __restrict__ skey)
{
    int p = blockIdx.x * 256 + threadIdx.x;
    int key = (p >> 16) * HWSZ + xy[2*p] * WGRID + xy[2*p + 1];
    unsigned o = offs[key];
    unsigned r = atomicAdd(&cur[key], 1u);
    unsigned slot = o + r;
    pidf[slot] = (unsigned)p | (r == 0 ? 0x80000000u : 0u);
    send[slot] = o + counts[key];
    skey[slot] = (unsigned)key;
}

// ---- Kernel 3 (MFMA): y2 = bf16(relu(bn1(y1)) @ W2) [P,128]; bn2 stats ----
__global__ __launch_bounds__(256, 2) void k_lin2(
    const float* __restrict__ y1, const float* __restrict__ g1,
    const float* __restrict__ b1, const uint4* __restrict__ W2F,
    const float* __restrict__ st1, unsigned short* __restrict__ y2,
    float* __restrict__ st2)
{
    __shared__ uint4 w2s[1024];        // 16 KB
    __shared__ float sc1s[64], sh1s[64];
    const int tid = threadIdx.x, l = tid & 63, w = tid >> 6;
    if (tid < 64) {
        float mu = st1[tid * 16] * (1.0f / CNTF);
        float var = st1[(64 + tid) * 16] * (1.0f / CNTF) - mu * mu;
        float rs = rsqrtf(var + EPS);
        sc1s[tid] = rs * g1[tid];
        sh1s[tid] = b1[tid] - mu * rs * g1[tid];
    }
    #pragma unroll
    for (int r = 0; r < 4; ++r) w2s[r * 256 + tid] = W2F[r * 256 + tid];
    __syncthreads();
    const int n = l & 31, q = l >> 5;
    float s_acc[16], q_acc[16];
    #pragma unroll
    for (int r = 0; r < 16; ++r) { s_acc[r] = 0.f; q_acc[r] = 0.f; }

    for (int t = 0; t < 8; ++t) {
        const int p = (blockIdx.x * 8 + t) * 32 + n;
        const float* yrow = y1 + (size_t)p * 64 + q * 8;
        bf16x8 Bf[4];
        #pragma unroll
        for (int ks = 0; ks < 4; ++ks) {
            float4 v0 = *(const float4*)(yrow + ks * 16);
            float4 v1 = *(const float4*)(yrow + ks * 16 + 4);
            int k0 = ks * 16 + q * 8;
            float e[8] = {v0.x,v0.y,v0.z,v0.w,v1.x,v1.y,v1.z,v1.w};
            union { bf16x8 v; unsigned u[4]; } cv;
            #pragma unroll
            for (int jj = 0; jj < 4; ++jj) {
                float a0 = fmaxf(fmaf(e[2*jj],   sc1s[k0+2*jj],   sh1s[k0+2*jj]),   0.f);
                float a1 = fmaxf(fmaf(e[2*jj+1], sc1s[k0+2*jj+1], sh1s[k0+2*jj+1]), 0.f);
                cv.u[jj] = f2bf(a0) | (f2bf(a1) << 16);
            }
            Bf[ks] = cv.v;
        }
        f32x16 acc;
        #pragma unroll
        for (int r = 0; r < 16; ++r) acc[r] = 0.f;
        #pragma unroll
        for (int ks = 0; ks < 4; ++ks) {
            union { uint4 u; bf16x8 v; } av;
            av.u = w2s[(w * 4 + ks) * 64 + l];
            acc = __builtin_amdgcn_mfma_f32_32x32x16_bf16(av.v, Bf[ks], acc, 0, 0, 0);
        }
        #pragma unroll
        for (int g = 0; g < 4; ++g) {
            int ch0 = w * 32 + 8 * g + 4 * q;
            ushort4 pk;
            pk.x = (unsigned short)f2bf(acc[4*g+0]);
            pk.y = (unsigned short)f2bf(acc[4*g+1]);
            pk.z = (unsigned short)f2bf(acc[4*g+2]);
            pk.w = (unsigned short)f2bf(acc[4*g+3]);
            *(ushort4*)(y2 + (size_t)p * 128 + ch0) = pk;
        }
        #pragma unroll
        for (int r = 0; r < 16; ++r) { s_acc[r] += acc[r]; q_acc[r] += acc[r]*acc[r]; }
    }
    #pragma unroll
    for (int r = 0; r < 16; ++r) {
        float s = s_acc[r], sq = q_acc[r];
        #pragma unroll
        for (int off = 16; off > 0; off >>= 1) {
            s  += __shfl_xor(s, off);
            sq += __shfl_xor(sq, off);
        }
        if ((l & 31) == 0) {
            int ch = w * 32 + (r & 3) + 8 * (r >> 2) + 4 * q;
            atomicAdd(&st2[ch * 16], s);
            atomicAdd(&st2[(128 + ch) * 16], sq);
        }
    }
}

// ---- Kernel 4 (MFMA): y3 = bf16(y2f @ W3) [P,256]; bn3 stats ----
__global__ __launch_bounds__(256, 2) void k_lin3(
    const unsigned short* __restrict__ y2f, const uint4* __restrict__ W3F,
    unsigned short* __restrict__ y3, float* __restrict__ st3)
{
    __shared__ uint4 w3s[4096];        // 64 KB
    const int tid = threadIdx.x, l = tid & 63, w = tid >> 6;
    #pragma unroll
    for (int r = 0; r < 16; ++r) w3s[r * 256 + tid] = W3F[r * 256 + tid];
    __syncthreads();
    const int n = l & 31, q = l >> 5;
    float s_acc[32], q_acc[32];
    #pragma unroll
    for (int r = 0; r < 32; ++r) { s_acc[r] = 0.f; q_acc[r] = 0.f; }

    for (int t = 0; t < 8; ++t) {
        const int p = (blockIdx.x * 8 + t) * 32 + n;
        const unsigned short* yrow = y2f + (size_t)p * 128 + q * 8;
        bf16x8 Bf[8];
        #pragma unroll
        for (int ks = 0; ks < 8; ++ks) {
            union { uint4 u; bf16x8 v; } bv;
            bv.u = *(const uint4*)(yrow + ks * 16);
            Bf[ks] = bv.v;
        }
        f32x16 acc[2];
        #pragma unroll
        for (int i = 0; i < 2; ++i)
            #pragma unroll
            for (int r = 0; r < 16; ++r) acc[i][r] = 0.f;
        #pragma unroll
        for (int ks = 0; ks < 8; ++ks) {
            #pragma unroll
            for (int i = 0; i < 2; ++i) {
                union { uint4 u; bf16x8 v; } av;
                av.u = w3s[((w * 2 + i) * 8 + ks) * 64 + l];
                acc[i] = __builtin_amdgcn_mfma_f32_32x32x16_bf16(av.v, Bf[ks], acc[i], 0, 0, 0);
            }
        }
        #pragma unroll
        for (int i = 0; i < 2; ++i) {
            #pragma unroll
            for (int g = 0; g < 4; ++g) {
                int ch0 = (w * 2 + i) * 32 + 8 * g + 4 * q;
                ushort4 pk;
                pk.x = (unsigned short)f2bf(acc[i][4*g+0]);
                pk.y = (unsigned short)f2bf(acc[i][4*g+1]);
                pk.z = (unsigned short)f2bf(acc[i][4*g+2]);
                pk.w = (unsigned short)f2bf(acc[i][4*g+3]);
                *(ushort4*)(y3 + (size_t)p * 256 + ch0) = pk;
            }
            #pragma unroll
            for (int r = 0; r < 16; ++r) {
                s_acc[i*16+r] += acc[i][r];
                q_acc[i*16+r] += acc[i][r] * acc[i][r];
            }
        }
    }
    #pragma unroll
    for (int i = 0; i < 2; ++i)
        #pragma unroll
        for (int r = 0; r < 16; ++r) {
            float s = s_acc[i*16+r], sq = q_acc[i*16+r];
            #pragma unroll
            for (int off = 16; off > 0; off >>= 1) {
                s  += __shfl_xor(s, off);
                sq += __shfl_xor(sq, off);
            }
            if ((l & 31) == 0) {
                int ch = (w * 2 + i) * 32 + (r & 3) + 8 * (r >> 2) + 4 * q;
                atomicAdd(&st3[ch * 16], s);
                atomicAdd(&st3[(256 + ch) * 16], sq);
            }
        }
}

// ---- Kernel 5 (MFMA): lane=channel GEMM + register segmented max ----
// blocks = 4 ms-quarters x 512 window-groups; wave w -> channel tile ms*4+w.
// Windows processed DESCENDING (t=8 computes carry only, no stores).
__global__ __launch_bounds__(256, 2) void k_smax(
    const unsigned short* __restrict__ y3f, const uint4* __restrict__ W4F,
    const unsigned* __restrict__ pidf, const unsigned* __restrict__ send,
    const unsigned* __restrict__ skey, unsigned short* __restrict__ pooled)
{
    const int tid = threadIdx.x, l = tid & 63, w = tid >> 6;
    const int ms = blockIdx.x & 3;
    const int wg = blockIdx.x >> 2;    // 0..511
    const int q = l >> 5;
    const int nt = ms * 4 + w;         // global channel tile (32 ch)

    // W4 fragments register-resident (B operand; same layout as A by symmetry)
    uint4 Wf[16];
    #pragma unroll
    for (int ks = 0; ks < 16; ++ks)
        Wf[ks] = W4F[(size_t)(nt * 16 + ks) * 64 + l];

    float s0c = -3.4e38f;              // carry: suffix-max at next window's pos 0
    for (int t = 8; t >= 0; --t) {
        const int p0 = (wg * 8 + t) * 32;
        int pos = p0 + (l & 31);
        int sp = pos < P_TOT ? pos : P_TOT - 1;
        unsigned pf = pidf[sp];
        unsigned e_l = send[sp];
        unsigned key_l = skey[sp];
        const unsigned short* row =
            y3f + (size_t)(pf & 0x7FFFFFFFu) * 256 + q * 8;
        f32x16 acc;
        #pragma unroll
        for (int r = 0; r < 16; ++r) acc[r] = 0.f;
        #pragma unroll
        for (int ks = 0; ks < 16; ++ks) {
            union { uint4 u; bf16x8 v; } xv;
            xv.u = *(const uint4*)(row + ks * 16);
            union { uint4 u; bf16x8 v; } wv;
            wv.u = Wf[ks];
            // A = X (M=points), B = W4 (N=channels) -> C: lane=channel, reg=point
            acc = __builtin_amdgcn_mfma_f32_32x32x16_bf16(xv.v, wv.v, acc, 0, 0, 0);
        }
        // half-exchange: build v[point 0..31] per lane (lane = channel)
        float v[32];
        #pragma unroll
        for (int r = 0; r < 16; ++r) {
            int base = (r & 3) + 8 * (r >> 2);   // rows for q=0
            float o = __shfl_xor(acc[r], 32);
            v[base]     = q ? o : acc[r];
            v[base + 4] = q ? acc[r] : o;
        }
        // serial segmented suffix-max, wave-uniform conditions via readlane
        {
            unsigned em = (unsigned)__builtin_amdgcn_readlane((int)e_l, 31);
            if ((unsigned)(p0 + 32) < em) v[31] = fmaxf(v[31], s0c);
        }
        #pragma unroll
        for (int m = 30; m >= 0; --m) {
            unsigned em = (unsigned)__builtin_amdgcn_readlane((int)e_l, m);
            if ((unsigned)(p0 + m + 1) < em) v[m] = fmaxf(v[m], v[m + 1]);
        }
        s0c = v[0];
        // stores: first-point rows only; halves split m ranges
        if (t < 8) {
            #pragma unroll
            for (int m = 0; m < 32; ++m) {
                int fm = __builtin_amdgcn_readlane((int)pf, m);
                if (fm < 0) {
                    unsigned km = (unsigned)__builtin_amdgcn_readlane((int)key_l, m);
                    if ((m >> 4) == q)
                        pooled[(size_t)km * 512 + nt * 32 + (l & 31)] =
                            (unsigned short)f2bf(v[m]);
                }
            }
        }
    }
}

// ---- Kernel 6 (MFMA): comp = relu(pooled @ Wc); transpose to [B,CMP,H,W] ----
__global__ __launch_bounds__(256, 4) void k_out(
    const unsigned short* __restrict__ pooled, const unsigned* __restrict__ counts,
    const uint4* __restrict__ WcF, float* __restrict__ out)
{
    __shared__ uint4 wcs[2048];        // 32 KB: full WcF
    const int tid = threadIdx.x, l = tid & 63, w = tid >> 6;
    const int sbase = blockIdx.x * 128;
    #pragma unroll
    for (int r = 0; r < 8; ++r) wcs[r * 256 + tid] = WcF[r * 256 + tid];
    __syncthreads();
    const int n = l & 31, q = l >> 5;
    const int s = sbase + w * 32 + n;
    const unsigned short* prow = pooled + (size_t)s * 512 + q * 8;
    f32x16 acc;
    #pragma unroll
    for (int r = 0; r < 16; ++r) acc[r] = 0.f;

    for (int ks = 0; ks < 32; ++ks) {
        union { uint4 u; bf16x8 v; } bv;
        bv.u = *(const uint4*)(prow + ks * 16);   // raw bf16 IS the B frag
        union { uint4 u; bf16x8 v; } av;
        av.u = wcs[ks * 64 + l];
        acc = __builtin_amdgcn_mfma_f32_32x32x16_bf16(av.v, bv.v, acc, 0, 0, 0);
    }
    const bool occ = counts[s] > 0;
    const int b = s >> 16, hw = s & 65535;
    #pragma unroll
    for (int r = 0; r < 16; ++r) {
        int ch = (r & 3) + 8 * (r >> 2) + 4 * q;
        float x = occ ? fmaxf(acc[r], 0.f) : 0.f;
        out[(size_t)b * (32 * HWSZ) + (size_t)ch * HWSZ + hw] = x;
    }
}

extern "C" void kernel_launch(void* const* d_in, const int* in_sizes, int n_in,
                              void* d_out, int out_size, void* d_ws, size_t ws_size,
                              hipStream_t stream) {
    const float* pt = (const float*)d_in[0];
    const float* g0 = (const float*)d_in[1];
    const float* b0 = (const float*)d_in[2];
    const float* W1 = (const float*)d_in[3];
    const float* g1 = (const float*)d_in[4];
    const float* b1 = (const float*)d_in[5];
    const float* W2 = (const float*)d_in[6];
    const float* g2 = (const float*)d_in[7];
    const float* b2 = (const float*)d_in[8];
    const float* W3 = (const float*)d_in[9];
    const float* g3 = (const float*)d_in[10];
    const float* b3 = (const float*)d_in[11];
    const float* W4 = (const float*)d_in[12];
    const float* Wc = (const float*)d_in[13];
    const int*   xy = (const int*)d_in[14];
    float* out = (float*)d_out;

    char* ws = (char*)d_ws;
    unsigned short* y3     = (unsigned short*)(ws + OFF_Y3);
    float*          y1     = (float*)(ws + OFF_Y1);
    unsigned short* y2     = (unsigned short*)(ws + OFF_Y2);
    unsigned short* pool16 = (unsigned short*)(ws + OFF_POOL);
    unsigned*       counts = (unsigned*)(ws + OFF_CNT);
    float*          st     = (float*)(ws + OFF_ST);
    unsigned*       offs   = (unsigned*)(ws + OFF_OFFS);
    unsigned*       cur    = (unsigned*)(ws + OFF_CUR);
    unsigned*       bsum   = (unsigned*)(ws + OFF_BSUM);
    unsigned*       pidf   = (unsigned*)(ws + OFF_PIDF);
    unsigned*       send   = (unsigned*)(ws + OFF_SEND);
    unsigned*       skey   = (unsigned*)(ws + OFF_SKEY);
    uint4* W3F = (uint4*)(ws + OFF_W3F);
    uint4* W4F = (uint4*)(ws + OFF_W4F);
    uint4* WcF = (uint4*)(ws + OFF_WCF);
    uint4* W2F = (uint4*)(ws + OFF_W2F);
    float* scsh = (float*)(ws + OFF_SCSH);
    float* sc2 = scsh;       float* sh2 = scsh + 128;
    float* sc3 = scsh + 256; float* sh3 = scsh + 512;
    // padded stats: one 64B line per entry (entry i at st[i*16])
    float* st0 = st;            // 16 entries
    float* st1 = st + 256;      // 128 entries
    float* st2 = st + 2304;     // 256 entries
    float* st3 = st + 6400;     // 512 entries

    // zero counts+stats+offs+cur in one contiguous pass (1638400 B)
    k_zero<<<400, 256, 0, stream>>>((uint4*)(ws + OFF_CNT), 102400);
    // weights -> bf16 frag layout
    k_prepw<<<92, 256, 0, stream>>>(W2, W3, W4, Wc, W2F, W3F, W4F, WcF);

    k_stats0<<<512, 256, 0, stream>>>(pt, xy, st0, counts);
    // counting sort: counts -> offs -> slot fill
    k_scan1<<<512, 256, 0, stream>>>(counts, bsum);
    k_scan2<<<1,   256, 0, stream>>>(bsum, bsum + 512);
    k_scan3<<<512, 256, 0, stream>>>(counts, bsum + 512, offs);
    k_fill<<<512, 256, 0, stream>>>(xy, offs, counts, cur, pidf, send, skey);

    k_lin1<<<512, 256, 0, stream>>>(pt, g0, b0, W1, st0, y1, st1);
    k_lin2<<<512, 256, 0, stream>>>(y1, g1, b1, W2F, st1, y2, st2);
    k_bnprep<<<1, 256, 0, stream>>>(st2, g2, b2, sc2, sh2, 128);
    k_fold<<<8192, 256, 0, stream>>>(y2, sc2, sh2, 128, 2097152);
    k_lin3<<<512, 256, 0, stream>>>(y2, W3F, y3, st3);
    k_bnprep<<<1, 256, 0, stream>>>(st3, g3, b3, sc3, sh3, 256);
    k_fold<<<16384, 256, 0, stream>>>(y3, sc3, sh3, 256, 4194304);

    k_smax<<<2048, 256, 0, stream>>>(y3, W4F, pidf, send, skey, pool16);
    k_out<<<S_TOT / 128, 256, 0, stream>>>(pool16, counts, WcF, out);
}

// Round 10
// 462.257 us; speedup vs baseline: 4.8558x; 1.0574x over previous
//
#include <hip/hip_runtime.h>
#include <cstdint>
#include <cstddef>

// PPmodel_all_preprocess — MI355X, round 10: k_smax v3 (ballot masks, X-in-regs,
// ms-merge).
//
// Round-9: k_smax 194us, all pipes idle -> latency-bound on (a) 63 readlane->
// SALU hazard chains per window, (b) 4x ms-split re-fetch of y3/metadata
// (FETCH 151MB vs 82MB ideal; XCD L2s don't share). Fix: 512 blocks (one per
// window-group, exactly 2/CU), X frags loaded ONCE into registers and reused
// across 4 sequential channel quarters (W4F streams from L2 interleaved with
// MFMA); segment/first conditions via ballot -> SGPR bit tests; readlane only
// for store keys. k_out: unoccupied rows redirected to line 0 (saves ~47MB
// poison fetch).
//
// Workspace layout (peak ~195.4 MiB): y3 | y1 | y2 | pooled(alias) | counts |
//   stats(padded x16) | offs | cur | bsum | pidf | send | skey | W3F | W4F |
//   WcF | W2F | scsh

#define P_TOT  131072
#define HWSZ   65536
#define WGRID  256
#define S_TOT  131072
#define EPS    1e-5f
#define CNTF   131072.0f

#define OFF_Y3    0ull
#define OFF_Y1    67108864ull
#define OFF_Y2    100663296ull
#define OFF_POOL  67108864ull
#define OFF_CNT   201326592ull
#define OFF_ST    201850880ull
#define OFF_OFFS  201916416ull
#define OFF_CUR   202440704ull
#define OFF_BSUM  202964992ull
#define OFF_PIDF  202969088ull
#define OFF_SEND  203493376ull
#define OFF_SKEY  204017664ull
#define OFF_W3F   204541952ull
#define OFF_W4F   204607488ull
#define OFF_WCF   204869632ull
#define OFF_W2F   204902400ull
#define OFF_SCSH  204918784ull

typedef __attribute__((ext_vector_type(8)))  short bf16x8;
typedef __attribute__((ext_vector_type(16))) float f32x16;

// ---- bf16 helpers (manual, RNE) ----
__device__ __forceinline__ unsigned f2bf(float f) {
    unsigned u = __float_as_uint(f);
    return (u + 0x7FFFu + ((u >> 16) & 1u)) >> 16;   // RNE, finite inputs
}
__device__ __forceinline__ float bf2f(unsigned h) {
    return __uint_as_float(h << 16);
}

// ---- zero-fill (graph-capture-safe memset replacement) ----
__global__ __launch_bounds__(256) void k_zero(uint4* __restrict__ p, int n_u4) {
    int i = blockIdx.x * blockDim.x + threadIdx.x;
    if (i < n_u4) p[i] = make_uint4(0u, 0u, 0u, 0u);
}

// ---- Prep: W2/W3/W4/Wc -> bf16 frag layout (32x32x16 operand) ----
__global__ __launch_bounds__(256) void k_prepw(
    const float* __restrict__ W2, const float* __restrict__ W3,
    const float* __restrict__ W4, const float* __restrict__ Wc,
    uint4* __restrict__ W2F, uint4* __restrict__ W3F,
    uint4* __restrict__ W4F, uint4* __restrict__ WcF)
{
    int gw = (blockIdx.x * 256 + threadIdx.x) >> 6;
    int l = threadIdx.x & 63;
    const float* W; uint4* dst; int M, mt, ks, fi;
    if (gw < 64)       { fi = gw;       W = W3; dst = W3F; M = 256; mt = fi >> 3; ks = fi & 7;  }
    else if (gw < 320) { fi = gw - 64;  W = W4; dst = W4F; M = 512; mt = fi >> 4; ks = fi & 15; }
    else if (gw < 352) { fi = gw - 320; W = Wc; dst = WcF; M = 32;  mt = 0;      ks = fi;      }
    else               { fi = gw - 352; W = W2; dst = W2F; M = 128; mt = fi >> 2; ks = fi & 3;  }
    int m = mt * 32 + (l & 31);
    int k0 = ks * 16 + (l >> 5) * 8;
    unsigned p[4];
    #pragma unroll
    for (int jj = 0; jj < 4; ++jj) {
        unsigned lo = f2bf(W[(size_t)(k0 + 2*jj)     * M + m]);
        unsigned hi = f2bf(W[(size_t)(k0 + 2*jj + 1) * M + m]);
        p[jj] = lo | (hi << 16);
    }
    dst[(size_t)fi * 64 + l] = make_uint4(p[0], p[1], p[2], p[3]);
}

// ---- bn fold coefficients: sc[c] = rs*g, sh[c] = b - mu*sc ----
__global__ __launch_bounds__(256) void k_bnprep(
    const float* __restrict__ st, const float* __restrict__ g,
    const float* __restrict__ b, float* __restrict__ sc,
    float* __restrict__ sh, int nch)
{
    int c = blockIdx.x * 256 + threadIdx.x;
    if (c >= nch) return;
    float mu = st[c * 16] * (1.0f / CNTF);
    float var = st[(nch + c) * 16] * (1.0f / CNTF) - mu * mu;
    float rs = rsqrtf(var + EPS);
    float s = rs * g[c];
    sc[c] = s;
    sh[c] = b[c] - mu * s;
}

// ---- In-place fold: y = bf16(relu(y*sc+sh)) for bf16 buffer, nch pow2 ----
__global__ __launch_bounds__(256) void k_fold(
    unsigned short* __restrict__ y, const float* __restrict__ sc,
    const float* __restrict__ sh, int nch, int n_u4)
{
    int i = blockIdx.x * 256 + threadIdx.x;
    if (i >= n_u4) return;
    int ch0 = (i * 8) & (nch - 1);
    float4 s0 = *(const float4*)(sc + ch0), s1 = *(const float4*)(sc + ch0 + 4);
    float4 h0 = *(const float4*)(sh + ch0), h1 = *(const float4*)(sh + ch0 + 4);
    float scv[8] = {s0.x,s0.y,s0.z,s0.w,s1.x,s1.y,s1.z,s1.w};
    float shv[8] = {h0.x,h0.y,h0.z,h0.w,h1.x,h1.y,h1.z,h1.w};
    uint4 e = ((const uint4*)y)[i];
    unsigned eu[4] = {e.x, e.y, e.z, e.w};
    unsigned ou[4];
    #pragma unroll
    for (int jj = 0; jj < 4; ++jj) {
        float x0 = fmaxf(fmaf(bf2f(eu[jj] & 0xFFFFu), scv[2*jj],   shv[2*jj]),   0.f);
        float x1 = fmaxf(fmaf(bf2f(eu[jj] >> 16),     scv[2*jj+1], shv[2*jj+1]), 0.f);
        ou[jj] = f2bf(x0) | (f2bf(x1) << 16);
    }
    ((uint4*)y)[i] = make_uint4(ou[0], ou[1], ou[2], ou[3]);
}

// ---- Kernel 1: bn0 raw stats (block-reduced) + per-voxel point counts ----
__global__ __launch_bounds__(256) void k_stats0(
    const float* __restrict__ pt, const int* __restrict__ xy,
    float* __restrict__ st0, unsigned* __restrict__ counts)
{
    __shared__ float part[4][16];
    const int tid = threadIdx.x;
    const int p = blockIdx.x * 256 + tid;
    const float4* f4 = (const float4*)(pt + (size_t)p * 8);
    float4 a = f4[0], b = f4[1];
    float v[8] = {a.x,a.y,a.z,a.w,b.x,b.y,b.z,b.w};
    int key = (p >> 16) * HWSZ + xy[2*p] * WGRID + xy[2*p + 1];
    atomicAdd(&counts[key], 1u);
    float s[8], q[8];
    #pragma unroll
    for (int k = 0; k < 8; ++k) { s[k] = v[k]; q[k] = v[k]*v[k]; }
    #pragma unroll
    for (int k = 0; k < 8; ++k) {
        #pragma unroll
        for (int off = 32; off > 0; off >>= 1) {
            s[k] += __shfl_down(s[k], off);
            q[k] += __shfl_down(q[k], off);
        }
    }
    if ((tid & 63) == 0) {
        int w = tid >> 6;
        #pragma unroll
        for (int k = 0; k < 8; ++k) { part[w][k] = s[k]; part[w][8 + k] = q[k]; }
    }
    __syncthreads();
    if (tid < 16) {
        float t = part[0][tid] + part[1][tid] + part[2][tid] + part[3][tid];
        atomicAdd(&st0[tid * 16], t);
    }
}

// ---- Kernel 2: x0 = bn0(feats); y1 = x0 @ W1 [P,64] f32; bn1 stats ----
__global__ __launch_bounds__(256) void k_lin1(
    const float* __restrict__ pt, const float* __restrict__ g0,
    const float* __restrict__ b0, const float* __restrict__ W1,
    const float* __restrict__ st0, float* __restrict__ y1,
    float* __restrict__ st1)
{
    __shared__ float x0s[64 * 8];
    __shared__ float w1s[8 * 64];
    __shared__ float sc0s[8], sh0s[8];
    __shared__ float red[256];
    const int tid = threadIdx.x;

    if (tid < 8) {
        float mu = st0[tid * 16] * (1.0f / CNTF);
        float var = st0[(8 + tid) * 16] * (1.0f / CNTF) - mu * mu;
        float rs = rsqrtf(var + EPS);
        sc0s[tid] = rs * g0[tid];
        sh0s[tid] = b0[tid] - mu * rs * g0[tid];
    }
    if (tid < 128) ((float4*)w1s)[tid] = ((const float4*)W1)[tid];
    const int c = tid & 63;
    const int psub = tid >> 6;
    float ssum = 0.f, ssq = 0.f;
    for (int t = 0; t < 4; ++t) {
        const int pbase = blockIdx.x * 256 + t * 64;
        __syncthreads();
        if (tid < 128) {
            float4 f = ((const float4*)(pt + (size_t)pbase * 8))[tid];
            int cc = (tid & 1) * 4;
            f.x = fmaf(f.x, sc0s[cc + 0], sh0s[cc + 0]);
            f.y = fmaf(f.y, sc0s[cc + 1], sh0s[cc + 1]);
            f.z = fmaf(f.z, sc0s[cc + 2], sh0s[cc + 2]);
            f.w = fmaf(f.w, sc0s[cc + 3], sh0s[cc + 3]);
            ((float4*)x0s)[tid] = f;
        }
        __syncthreads();
        #pragma unroll
        for (int i = 0; i < 16; ++i) {
            int pl = psub * 16 + i;
            float acc = 0.f;
            #pragma unroll
            for (int k = 0; k < 8; ++k)
                acc = fmaf(x0s[pl * 8 + k], w1s[k * 64 + c], acc);
            y1[(size_t)(pbase + pl) * 64 + c] = acc;
            ssum += acc; ssq += acc * acc;
        }
    }
    red[tid] = ssum; __syncthreads();
    if (tid < 64) atomicAdd(&st1[tid * 16],
        red[tid] + red[tid+64] + red[tid+128] + red[tid+192]);
    __syncthreads();
    red[tid] = ssq; __syncthreads();
    if (tid < 64) atomicAdd(&st1[(64 + tid) * 16],
        red[tid] + red[tid+64] + red[tid+128] + red[tid+192]);
}

// ---- Scan kernels: counts -> exclusive offsets ----
__global__ __launch_bounds__(256) void k_scan1(
    const unsigned* __restrict__ counts, unsigned* __restrict__ bsum)
{
    __shared__ unsigned sh[256];
    int t = threadIdx.x;
    sh[t] = counts[blockIdx.x * 256 + t];
    __syncthreads();
    for (int d = 128; d > 0; d >>= 1) {
        if (t < d) sh[t] += sh[t + d];
        __syncthreads();
    }
    if (t == 0) bsum[blockIdx.x] = sh[0];
}

__global__ __launch_bounds__(256) void k_scan2(
    const unsigned* __restrict__ bsum, unsigned* __restrict__ boff)
{
    __shared__ unsigned sh[256];
    int t = threadIdx.x;
    unsigned a = bsum[2*t], b = bsum[2*t+1];
    unsigned s = a + b;
    sh[t] = s; __syncthreads();
    for (int d = 1; d < 256; d <<= 1) {
        unsigned u = (t >= d) ? sh[t-d] : 0u;
        __syncthreads();
        sh[t] += u;
        __syncthreads();
    }
    unsigned excl = sh[t] - s;
    boff[2*t]   = excl;
    boff[2*t+1] = excl + a;
}

__global__ __launch_bounds__(256) void k_scan3(
    const unsigned* __restrict__ counts, const unsigned* __restrict__ boff,
    unsigned* __restrict__ offs)
{
    __shared__ unsigned sh[256];
    int t = threadIdx.x, b = blockIdx.x;
    unsigned v = counts[b*256 + t];
    sh[t] = v; __syncthreads();
    for (int d = 1; d < 256; d <<= 1) {
        unsigned u = (t >= d) ? sh[t-d] : 0u;
        __syncthreads();
        sh[t] += u;
        __syncthreads();
    }
    offs[b*256 + t] = boff[b] + sh[t] - v;
}

// ---- Fill: bucket points by voxel ----
__global__ __launch_bounds__(256) void k_fill(
    const int* __restrict__ xy, const unsigned* __restrict__ offs,
    const unsigned* __restrict__ counts, unsigned* __restrict__ cur,
    unsigned* __restrict__ pidf, unsigned* __restrict__ send,
    unsigned* __restrict__ skey)
{
    int p = blockIdx.x * 256 + threadIdx.x;
    int key = (p >> 16) * HWSZ + xy[2*p] * WGRID + xy[2*p + 1];
    unsigned o = offs[key];
    unsigned r = atomicAdd(&cur[key], 1u);
    unsigned slot = o + r;
    pidf[slot] = (unsigned)p | (r == 0 ? 0x80000000u : 0u);
    send[slot] = o + counts[key];
    skey[slot] = (unsigned)key;
}

// ---- Kernel 3 (MFMA): y2 = bf16(relu(bn1(y1)) @ W2) [P,128]; bn2 stats ----
__global__ __launch_bounds__(256, 2) void k_lin2(
    const float* __restrict__ y1, const float* __restrict__ g1,
    const float* __restrict__ b1, const uint4* __restrict__ W2F,
    const float* __restrict__ st1, unsigned short* __restrict__ y2,
    float* __restrict__ st2)
{
    __shared__ uint4 w2s[1024];        // 16 KB
    __shared__ float sc1s[64], sh1s[64];
    const int tid = threadIdx.x, l = tid & 63, w = tid >> 6;
    if (tid < 64) {
        float mu = st1[tid * 16] * (1.0f / CNTF);
        float var = st1[(64 + tid) * 16] * (1.0f / CNTF) - mu * mu;
        float rs = rsqrtf(var + EPS);
        sc1s[tid] = rs * g1[tid];
        sh1s[tid] = b1[tid] - mu * rs * g1[tid];
    }
    #pragma unroll
    for (int r = 0; r < 4; ++r) w2s[r * 256 + tid] = W2F[r * 256 + tid];
    __syncthreads();
    const int n = l & 31, q = l >> 5;
    float s_acc[16], q_acc[16];
    #pragma unroll
    for (int r = 0; r < 16; ++r) { s_acc[r] = 0.f; q_acc[r] = 0.f; }

    for (int t = 0; t < 8; ++t) {
        const int p = (blockIdx.x * 8 + t) * 32 + n;
        const float* yrow = y1 + (size_t)p * 64 + q * 8;
        bf16x8 Bf[4];
        #pragma unroll
        for (int ks = 0; ks < 4; ++ks) {
            float4 v0 = *(const float4*)(yrow + ks * 16);
            float4 v1 = *(const float4*)(yrow + ks * 16 + 4);
            int k0 = ks * 16 + q * 8;
            float e[8] = {v0.x,v0.y,v0.z,v0.w,v1.x,v1.y,v1.z,v1.w};
            union { bf16x8 v; unsigned u[4]; } cv;
            #pragma unroll
            for (int jj = 0; jj < 4; ++jj) {
                float a0 = fmaxf(fmaf(e[2*jj],   sc1s[k0+2*jj],   sh1s[k0+2*jj]),   0.f);
                float a1 = fmaxf(fmaf(e[2*jj+1], sc1s[k0+2*jj+1], sh1s[k0+2*jj+1]), 0.f);
                cv.u[jj] = f2bf(a0) | (f2bf(a1) << 16);
            }
            Bf[ks] = cv.v;
        }
        f32x16 acc;
        #pragma unroll
        for (int r = 0; r < 16; ++r) acc[r] = 0.f;
        #pragma unroll
        for (int ks = 0; ks < 4; ++ks) {
            union { uint4 u; bf16x8 v; } av;
            av.u = w2s[(w * 4 + ks) * 64 + l];
            acc = __builtin_amdgcn_mfma_f32_32x32x16_bf16(av.v, Bf[ks], acc, 0, 0, 0);
        }
        #pragma unroll
        for (int g = 0; g < 4; ++g) {
            int ch0 = w * 32 + 8 * g + 4 * q;
            ushort4 pk;
            pk.x = (unsigned short)f2bf(acc[4*g+0]);
            pk.y = (unsigned short)f2bf(acc[4*g+1]);
            pk.z = (unsigned short)f2bf(acc[4*g+2]);
            pk.w = (unsigned short)f2bf(acc[4*g+3]);
            *(ushort4*)(y2 + (size_t)p * 128 + ch0) = pk;
        }
        #pragma unroll
        for (int r = 0; r < 16; ++r) { s_acc[r] += acc[r]; q_acc[r] += acc[r]*acc[r]; }
    }
    #pragma unroll
    for (int r = 0; r < 16; ++r) {
        float s = s_acc[r], sq = q_acc[r];
        #pragma unroll
        for (int off = 16; off > 0; off >>= 1) {
            s  += __shfl_xor(s, off);
            sq += __shfl_xor(sq, off);
        }
        if ((l & 31) == 0) {
            int ch = w * 32 + (r & 3) + 8 * (r >> 2) + 4 * q;
            atomicAdd(&st2[ch * 16], s);
            atomicAdd(&st2[(128 + ch) * 16], sq);
        }
    }
}

// ---- Kernel 4 (MFMA): y3 = bf16(y2f @ W3) [P,256]; bn3 stats ----
__global__ __launch_bounds__(256, 2) void k_lin3(
    const unsigned short* __restrict__ y2f, const uint4* __restrict__ W3F,
    unsigned short* __restrict__ y3, float* __restrict__ st3)
{
    __shared__ uint4 w3s[4096];        // 64 KB
    const int tid = threadIdx.x, l = tid & 63, w = tid >> 6;
    #pragma unroll
    for (int r = 0; r < 16; ++r) w3s[r * 256 + tid] = W3F[r * 256 + tid];
    __syncthreads();
    const int n = l & 31, q = l >> 5;
    float s_acc[32], q_acc[32];
    #pragma unroll
    for (int r = 0; r < 32; ++r) { s_acc[r] = 0.f; q_acc[r] = 0.f; }

    for (int t = 0; t < 8; ++t) {
        const int p = (blockIdx.x * 8 + t) * 32 + n;
        const unsigned short* yrow = y2f + (size_t)p * 128 + q * 8;
        bf16x8 Bf[8];
        #pragma unroll
        for (int ks = 0; ks < 8; ++ks) {
            union { uint4 u; bf16x8 v; } bv;
            bv.u = *(const uint4*)(yrow + ks * 16);
            Bf[ks] = bv.v;
        }
        f32x16 acc[2];
        #pragma unroll
        for (int i = 0; i < 2; ++i)
            #pragma unroll
            for (int r = 0; r < 16; ++r) acc[i][r] = 0.f;
        #pragma unroll
        for (int ks = 0; ks < 8; ++ks) {
            #pragma unroll
            for (int i = 0; i < 2; ++i) {
                union { uint4 u; bf16x8 v; } av;
                av.u = w3s[((w * 2 + i) * 8 + ks) * 64 + l];
                acc[i] = __builtin_amdgcn_mfma_f32_32x32x16_bf16(av.v, Bf[ks], acc[i], 0, 0, 0);
            }
        }
        #pragma unroll
        for (int i = 0; i < 2; ++i) {
            #pragma unroll
            for (int g = 0; g < 4; ++g) {
                int ch0 = (w * 2 + i) * 32 + 8 * g + 4 * q;
                ushort4 pk;
                pk.x = (unsigned short)f2bf(acc[i][4*g+0]);
                pk.y = (unsigned short)f2bf(acc[i][4*g+1]);
                pk.z = (unsigned short)f2bf(acc[i][4*g+2]);
                pk.w = (unsigned short)f2bf(acc[i][4*g+3]);
                *(ushort4*)(y3 + (size_t)p * 256 + ch0) = pk;
            }
            #pragma unroll
            for (int r = 0; r < 16; ++r) {
                s_acc[i*16+r] += acc[i][r];
                q_acc[i*16+r] += acc[i][r] * acc[i][r];
            }
        }
    }
    #pragma unroll
    for (int i = 0; i < 2; ++i)
        #pragma unroll
        for (int r = 0; r < 16; ++r) {
            float s = s_acc[i*16+r], sq = q_acc[i*16+r];
            #pragma unroll
            for (int off = 16; off > 0; off >>= 1) {
                s  += __shfl_xor(s, off);
                sq += __shfl_xor(sq, off);
            }
            if ((l & 31) == 0) {
                int ch = (w * 2 + i) * 32 + (r & 3) + 8 * (r >> 2) + 4 * q;
                atomicAdd(&st3[ch * 16], s);
                atomicAdd(&st3[(256 + ch) * 16], sq);
            }
        }
}

// ---- Kernel 5 (MFMA): X-in-regs GEMM + ballot-mask register segmented max ----
// 512 blocks (one per window-group, 2/CU); wave w handles channel tiles
// nt = sub*4+w for sub=0..3 sequentially, X frags reused. Windows descending,
// t=8 is carry-only overlap.
__global__ __launch_bounds__(256, 2) void k_smax(
    const unsigned short* __restrict__ y3f, const uint4* __restrict__ W4F,
    const unsigned* __restrict__ pidf, const unsigned* __restrict__ send,
    const unsigned* __restrict__ skey, unsigned short* __restrict__ pooled)
{
    const int tid = threadIdx.x, l = tid & 63, w = tid >> 6;
    const int wg = blockIdx.x;         // 0..511
    const int q = l >> 5;

    float s0c[4] = {-3.4e38f, -3.4e38f, -3.4e38f, -3.4e38f};
    #pragma unroll 1
    for (int t = 8; t >= 0; --t) {
        const int p0 = (wg * 8 + t) * 32;
        const int pos = p0 + (l & 31);
        const int sp = pos < P_TOT ? pos : P_TOT - 1;
        const unsigned pf = pidf[sp];
        const unsigned e_l = send[sp];
        const unsigned key_l = skey[sp];
        // wave-uniform masks (bits 0..31; halves duplicate)
        const unsigned cmask =
            (unsigned)__ballot((unsigned)(pos + 1) < e_l);
        const unsigned fmask =
            (unsigned)__ballot((pf & 0x80000000u) != 0u);
        // X fragments once (A operand: lane=point, 8 ch each), reused 4x
        const unsigned short* row =
            y3f + (size_t)(pf & 0x7FFFFFFFu) * 256 + q * 8;
        uint4 Xf[16];
        #pragma unroll
        for (int ks = 0; ks < 16; ++ks)
            Xf[ks] = *(const uint4*)(row + ks * 16);

        #pragma unroll 1
        for (int sub = 0; sub < 4; ++sub) {
            const int nt = sub * 4 + w;          // channel tile (32 ch)
            f32x16 acc;
            #pragma unroll
            for (int r = 0; r < 16; ++r) acc[r] = 0.f;
            #pragma unroll
            for (int ks = 0; ks < 16; ++ks) {
                union { uint4 u; bf16x8 v; } xv, wv;
                xv.u = Xf[ks];
                wv.u = W4F[(size_t)(nt * 16 + ks) * 64 + l];
                // A=X (M=points), B=W4 (N=channels) -> C: lane=ch, reg=point
                acc = __builtin_amdgcn_mfma_f32_32x32x16_bf16(xv.v, wv.v, acc, 0, 0, 0);
            }
            // half-exchange: v[point 0..31] per lane (lane = channel)
            float v[32];
            #pragma unroll
            for (int r = 0; r < 16; ++r) {
                int base = (r & 3) + 8 * (r >> 2);
                float o = __shfl_xor(acc[r], 32);
                v[base]     = q ? o : acc[r];
                v[base + 4] = q ? acc[r] : o;
            }
            // segmented suffix-max, SGPR-bit conditions (no readlane)
            if ((cmask >> 31) & 1) v[31] = fmaxf(v[31], s0c[sub]);
            #pragma unroll
            for (int m = 30; m >= 0; --m)
                if ((cmask >> m) & 1) v[m] = fmaxf(v[m], v[m + 1]);
            s0c[sub] = v[0];
            // stores: iterate first-point bits only (~20/window)
            if (t < 8) {
                unsigned fm = fmask;
                while (fm) {
                    int m = __ffs(fm) - 1;
                    fm &= fm - 1;
                    unsigned km = (unsigned)__builtin_amdgcn_readlane((int)key_l, m);
                    if ((m >> 4) == q)
                        pooled[(size_t)km * 512 + nt * 32 + (l & 31)] =
                            (unsigned short)f2bf(v[m]);
                }
            }
        }
    }
}

// ---- Kernel 6 (MFMA): comp = relu(pooled @ Wc); transpose to [B,CMP,H,W] ----
__global__ __launch_bounds__(256, 4) void k_out(
    const unsigned short* __restrict__ pooled, const unsigned* __restrict__ counts,
    const uint4* __restrict__ WcF, float* __restrict__ out)
{
    __shared__ uint4 wcs[2048];        // 32 KB: full WcF
    const int tid = threadIdx.x, l = tid & 63, w = tid >> 6;
    const int sbase = blockIdx.x * 128;
    #pragma unroll
    for (int r = 0; r < 8; ++r) wcs[r * 256 + tid] = WcF[r * 256 + tid];
    __syncthreads();
    const int n = l & 31, q = l >> 5;
    const int s = sbase + w * 32 + n;
    const bool occ = counts[s] > 0;
    // unoccupied voxels read the (hot) line-0 row instead of cold poison
    const unsigned short* prow =
        pooled + (occ ? (size_t)s * 512 : (size_t)0) + q * 8;
    f32x16 acc;
    #pragma unroll
    for (int r = 0; r < 16; ++r) acc[r] = 0.f;

    for (int ks = 0; ks < 32; ++ks) {
        union { uint4 u; bf16x8 v; } bv;
        bv.u = *(const uint4*)(prow + ks * 16);   // raw bf16 IS the B frag
        union { uint4 u; bf16x8 v; } av;
        av.u = wcs[ks * 64 + l];
        acc = __builtin_amdgcn_mfma_f32_32x32x16_bf16(av.v, bv.v, acc, 0, 0, 0);
    }
    const int b = s >> 16, hw = s & 65535;
    #pragma unroll
    for (int r = 0; r < 16; ++r) {
        int ch = (r & 3) + 8 * (r >> 2) + 4 * q;
        float x = occ ? fmaxf(acc[r], 0.f) : 0.f;
        out[(size_t)b * (32 * HWSZ) + (size_t)ch * HWSZ + hw] = x;
    }
}

extern "C" void kernel_launch(void* const* d_in, const int* in_sizes, int n_in,
                              void* d_out, int out_size, void* d_ws, size_t ws_size,
                              hipStream_t stream) {
    const float* pt = (const float*)d_in[0];
    const float* g0 = (const float*)d_in[1];
    const float* b0 = (const float*)d_in[2];
    const float* W1 = (const float*)d_in[3];
    const float* g1 = (const float*)d_in[4];
    const float* b1 = (const float*)d_in[5];
    const float* W2 = (const float*)d_in[6];
    const float* g2 = (const float*)d_in[7];
    const float* b2 = (const float*)d_in[8];
    const float* W3 = (const float*)d_in[9];
    const float* g3 = (const float*)d_in[10];
    const float* b3 = (const float*)d_in[11];
    const float* W4 = (const float*)d_in[12];
    const float* Wc = (const float*)d_in[13];
    const int*   xy = (const int*)d_in[14];
    float* out = (float*)d_out;

    char* ws = (char*)d_ws;
    unsigned short* y3     = (unsigned short*)(ws + OFF_Y3);
    float*          y1     = (float*)(ws + OFF_Y1);
    unsigned short* y2     = (unsigned short*)(ws + OFF_Y2);
    unsigned short* pool16 = (unsigned short*)(ws + OFF_POOL);
    unsigned*       counts = (unsigned*)(ws + OFF_CNT);
    float*          st     = (float*)(ws + OFF_ST);
    unsigned*       offs   = (unsigned*)(ws + OFF_OFFS);
    unsigned*       cur    = (unsigned*)(ws + OFF_CUR);
    unsigned*       bsum   = (unsigned*)(ws + OFF_BSUM);
    unsigned*       pidf   = (unsigned*)(ws + OFF_PIDF);
    unsigned*       send   = (unsigned*)(ws + OFF_SEND);
    unsigned*       skey   = (unsigned*)(ws + OFF_SKEY);
    uint4* W3F = (uint4*)(ws + OFF_W3F);
    uint4* W4F = (uint4*)(ws + OFF_W4F);
    uint4* WcF = (uint4*)(ws + OFF_WCF);
    uint4* W2F = (uint4*)(ws + OFF_W2F);
    float* scsh = (float*)(ws + OFF_SCSH);
    float* sc2 = scsh;       float* sh2 = scsh + 128;
    float* sc3 = scsh + 256; float* sh3 = scsh + 512;
    // padded stats: one 64B line per entry (entry i at st[i*16])
    float* st0 = st;            // 16 entries
    float* st1 = st + 256;      // 128 entries
    float* st2 = st + 2304;     // 256 entries
    float* st3 = st + 6400;     // 512 entries

    // zero counts+stats+offs+cur in one contiguous pass (1638400 B)
    k_zero<<<400, 256, 0, stream>>>((uint4*)(ws + OFF_CNT), 102400);
    // weights -> bf16 frag layout
    k_prepw<<<92, 256, 0, stream>>>(W2, W3, W4, Wc, W2F, W3F, W4F, WcF);

    k_stats0<<<512, 256, 0, stream>>>(pt, xy, st0, counts);
    // counting sort: counts -> offs -> slot fill
    k_scan1<<<512, 256, 0, stream>>>(counts, bsum);
    k_scan2<<<1,   256, 0, stream>>>(bsum, bsum + 512);
    k_scan3<<<512, 256, 0, stream>>>(counts, bsum + 512, offs);
    k_fill<<<512, 256, 0, stream>>>(xy, offs, counts, cur, pidf, send, skey);

    k_lin1<<<512, 256, 0, stream>>>(pt, g0, b0, W1, st0, y1, st1);
    k_lin2<<<512, 256, 0, stream>>>(y1, g1, b1, W2F, st1, y2, st2);
    k_bnprep<<<1, 256, 0, stream>>>(st2, g2, b2, sc2, sh2, 128);
    k_fold<<<8192, 256, 0, stream>>>(y2, sc2, sh2, 128, 2097152);
    k_lin3<<<512, 256, 0, stream>>>(y2, W3F, y3, st3);
    k_bnprep<<<1, 256, 0, stream>>>(st3, g3, b3, sc3, sh3, 256);
    k_fold<<<16384, 256, 0, stream>>>(y3, sc3, sh3, 256, 4194304);

    k_smax<<<512, 256, 0, stream>>>(y3, W4F, pidf, send, skey, pool16);
    k_out<<<S_TOT / 128, 256, 0, stream>>>(pool16, counts, WcF, out);
}